// Round 5
// baseline (295.374 us; speedup 1.0000x reference)
//
#include <hip/hip_runtime.h>
#include <math.h>

#define L_ 32
#define B_ 4
#define N_ 1000
#define D_ 128
#define H_ 8
#define DH_ 16
#define KN_ 8
#define M_ (L_ * B_ * N_)  // 128000 rows

typedef __attribute__((ext_vector_type(8))) short short8;
typedef __attribute__((ext_vector_type(8))) unsigned short ushort8v;
typedef __attribute__((ext_vector_type(4))) float floatx4;
typedef __attribute__((ext_vector_type(4))) unsigned uintx4;

static __device__ __forceinline__ unsigned short f2bf(float f) {
  union { float f; unsigned u; } v; v.f = f;
  unsigned r = v.u + 0x7fffu + ((v.u >> 16) & 1u);
  return (unsigned short)(r >> 16);
}
static __device__ __forceinline__ float bf2f(unsigned short s) {
  union { unsigned u; float f; } v; v.u = ((unsigned)s) << 16;
  return v.f;
}
// packed 2xf32 -> 2xbf16 (RNE), 1 VALU inst
static __device__ __forceinline__ unsigned cvtpk(float lo, float hi) {
  unsigned r;
  asm("v_cvt_pk_bf16_f32 %0, %1, %2" : "=v"(r) : "v"(lo), "v"(hi));
  return r;
}
static __device__ __forceinline__ float vexp2(float x) {  // 2^x
  float r; asm("v_exp_f32 %0, %1" : "=v"(r) : "v"(x)); return r;
}
static __device__ __forceinline__ float vrcp(float x) {  // ~1ulp 1/x
  float r; asm("v_rcp_f32 %0, %1" : "=v"(r) : "v"(x)); return r;
}
union B8 { uintx4 u; short8 s; };
union BW8 { uintx4 u; ushort8v s; };
// async global->LDS, 16B per lane; LDS dest is wave-uniform base + lane*16.
static __device__ __forceinline__ void gload_lds16(const unsigned short* g,
                                                   unsigned short* l) {
  __builtin_amdgcn_global_load_lds(
      (const __attribute__((address_space(1))) unsigned int*)g,
      (__attribute__((address_space(3))) unsigned int*)l, 16, 0, 0);
}

// ---------------------------------------------------------------------------
// prep: fp32 -> bf16 128x128 tile-images in LDS byte order (XOR-swizzled
// 16B granules: granule g of row m lands at m*16 + (g^(m&7))).
// Blocks 0..999: x tiles. 1000..1007: weight tiles
// (0-2 t_in, 3-5 s_in, 6 t_out, 7 s_out).
// ---------------------------------------------------------------------------
__global__ __launch_bounds__(256) void prep_kernel(
    const float* __restrict__ x, const float* __restrict__ wt_in,
    const float* __restrict__ ws_in, const float* __restrict__ wt_out,
    const float* __restrict__ ws_out, unsigned short* __restrict__ ximg,
    unsigned short* __restrict__ wimg) {
  const int bid = blockIdx.x, t = threadIdx.x;
  const float* src;
  unsigned short* dst;
  if (bid < 1000) {
    src = x + (size_t)bid * 16384;
    dst = ximg + (size_t)bid * 16384;
  } else {
    int w = bid - 1000;
    if (w < 3) src = wt_in + (size_t)w * 16384;
    else if (w < 6) src = ws_in + (size_t)(w - 3) * 16384;
    else if (w == 6) src = wt_out;
    else src = ws_out;
    dst = wimg + (size_t)w * 16384;
  }
#pragma unroll
  for (int it = 0; it < 8; ++it) {
    int gi = it * 256 + t;  // 0..2047
    int m = gi >> 4, g = gi & 15;
    const float4* sp = (const float4*)(src + m * 128 + g * 8);
    float4 a = sp[0], b = sp[1];
    ushort8v o;
    o[0] = f2bf(a.x); o[1] = f2bf(a.y); o[2] = f2bf(a.z); o[3] = f2bf(a.w);
    o[4] = f2bf(b.x); o[5] = f2bf(b.y); o[6] = f2bf(b.z); o[7] = f2bf(b.w);
    *(ushort8v*)(dst + (size_t)(m * 16 + (g ^ (m & 7))) * 8) = o;
  }
}

// ---------------------------------------------------------------------------
// proj_mfma: qkv(M,384) bf16 = x @ W^T + bias. Pure-DMA staging of
// pre-swizzled images; 128x128 tile; 4x4 grid of 16x16x32 bf16 MFMAs/wave.
// (used only for the spatial path)
// ---------------------------------------------------------------------------
__global__ __launch_bounds__(256) void proj_mfma(
    const unsigned short* __restrict__ ximg,
    const unsigned short* __restrict__ wimg, const float* __restrict__ bias,
    unsigned short* __restrict__ out) {
  __shared__ unsigned short As[128 * 128];
  __shared__ unsigned short Bs[128 * 128];
  const int t = threadIdx.x;
  const int bm = blockIdx.x / 3, bn = blockIdx.x % 3;
  const unsigned short* aSrc = ximg + (size_t)bm * 16384;
  const unsigned short* bSrc = wimg + (size_t)bn * 16384;
#pragma unroll
  for (int it = 0; it < 8; ++it) {
    int gi = it * 256 + t;
    gload_lds16(aSrc + (size_t)gi * 8, &As[gi * 8]);
    gload_lds16(bSrc + (size_t)gi * 8, &Bs[gi * 8]);
  }
  __syncthreads();
  const int wave = t >> 6, lane = t & 63;
  const int wm = (wave >> 1) * 64, wn = (wave & 1) * 64;
  const int lq = lane >> 4, l16 = lane & 15;
  floatx4 acc[4][4] = {};
#pragma unroll
  for (int kk = 0; kk < 4; ++kk) {
    int g = kk * 4 + lq;
    short8 a[4], b[4];
#pragma unroll
    for (int i = 0; i < 4; ++i) {
      int ma = wm + i * 16 + l16;
      a[i] = *(const short8*)(&As[(ma * 16 + (g ^ (ma & 7))) * 8]);
      int nb = wn + i * 16 + l16;
      b[i] = *(const short8*)(&Bs[(nb * 16 + (g ^ (nb & 7))) * 8]);
    }
#pragma unroll
    for (int i = 0; i < 4; ++i)
#pragma unroll
      for (int j = 0; j < 4; ++j)
        acc[i][j] = __builtin_amdgcn_mfma_f32_16x16x32_bf16(a[i], b[j],
                                                            acc[i][j], 0, 0, 0);
  }
  const size_t rowBase = (size_t)bm * 128 + wm;
  const int colBase = bn * 128 + wn;
#pragma unroll
  for (int j = 0; j < 4; ++j) {
    float bb = bias[colBase + j * 16 + l16];
#pragma unroll
    for (int i = 0; i < 4; ++i) {
#pragma unroll
      for (int r = 0; r < 4; ++r) {
        size_t row = rowBase + i * 16 + lq * 4 + r;
        out[row * 384 + colBase + j * 16 + l16] = f2bf(acc[i][j][r] + bb);
      }
    }
  }
}

// ---------------------------------------------------------------------------
// tattn_fused (R11, unchanged from R4): projection + temporal attention.
// One block per (b,n), 4 waves; wave w owns heads 2w,2w+1. bf16 packing via
// v_cvt_pk_bf16_f32; exp via v_exp_f32 (log2-domain); 1/sum via v_rcp_f32.
// V stays in registers (pi-pairing); Q,K transposed through 32x40 LDS.
// ---------------------------------------------------------------------------
__global__ __launch_bounds__(256) void tattn_fused(
    const unsigned short* __restrict__ ximg,
    const unsigned short* __restrict__ wimg,  // t_in slabs 0..2
    const float* __restrict__ bias,           // t_in_b[384]
    unsigned short* __restrict__ oimg) {
  __shared__ unsigned short Sx[512 * 8];         // 8KB: x rows 0..31
  __shared__ unsigned short Sqk[4][2][32 * 40];  // 20KB: per-wave Q,K scratch
  const int t = threadIdx.x;
  const int b = blockIdx.x / N_;
  const int n = blockIdx.x % N_;
  const int c = b * N_ + n;
  // --- stage x rows l=0..31 (global row rg = l*4000 + c) ---
#pragma unroll
  for (int it = 0; it < 2; ++it) {
    const int s = it * 256 + t;
    const int ml = s >> 4, gs = s & 15;
    const int G = gs ^ (ml & 7);  // dest slot gs holds granule G
    const size_t rg = (size_t)ml * (B_ * N_) + c;
    gload_lds16(ximg + (rg >> 7) * 16384 +
                    ((rg & 127) * 16 + (size_t)(G ^ ((int)rg & 7))) * 8,
                &Sx[s * 8]);
  }
  asm volatile("s_waitcnt vmcnt(0)" ::: "memory");
  __syncthreads();

  const int wv = t >> 6, lane = t & 63;
  const int lq = lane >> 4, l16 = lane & 15;

  // --- projection: Q,K,V (32 rows x 32 cols) for this wave's head pair ---
  floatx4 aQ[2][2] = {}, aK[2][2] = {}, aV[2][2] = {};
#pragma unroll
  for (int kk = 0; kk < 4; ++kk) {
    short8 a[2];
#pragma unroll
    for (int i = 0; i < 2; ++i) {
      const int ml = i * 16 + l16;
      a[i] = *(const short8*)&Sx[(ml * 16 + ((kk * 4 + lq) ^ (ml & 7))) * 8];
    }
#pragma unroll
    for (int mat = 0; mat < 3; ++mat) {
      const unsigned short* wb = wimg + mat * 16384;
      short8 bf[2];
#pragma unroll
      for (int j = 0; j < 2; ++j) {
        const int nb = wv * 32 + j * 16 + l16;
        bf[j] =
            *(const short8*)&wb[(nb * 16 + ((kk * 4 + lq) ^ (nb & 7))) * 8];
      }
#pragma unroll
      for (int i = 0; i < 2; ++i)
#pragma unroll
        for (int j = 0; j < 2; ++j) {
          floatx4* acc = mat == 0 ? &aQ[i][j] : (mat == 1 ? &aK[i][j] : &aV[i][j]);
          *acc = __builtin_amdgcn_mfma_f32_16x16x32_bf16(a[i], bf[j], *acc, 0,
                                                         0, 0);
        }
    }
  }
  // --- bias + write Q,K to per-wave scratch (cvt_pk, rows stride 40) ---
  const float bQ0 = bias[wv * 32 + l16], bQ1 = bias[wv * 32 + 16 + l16];
  const float bK0 = bias[128 + wv * 32 + l16],
              bK1 = bias[128 + wv * 32 + 16 + l16];
  const float bV0 = bias[256 + wv * 32 + l16],
              bV1 = bias[256 + wv * 32 + 16 + l16];
  unsigned short* Sq = Sqk[wv][0];
  unsigned short* Sk = Sqk[wv][1];
#pragma unroll
  for (int i = 0; i < 2; ++i)
#pragma unroll
    for (int j = 0; j < 2; ++j) {
      const float qb_ = j ? bQ1 : bQ0, kb_ = j ? bK1 : bK0;
      const unsigned q01 = cvtpk(aQ[i][j][0] + qb_, aQ[i][j][1] + qb_);
      const unsigned q23 = cvtpk(aQ[i][j][2] + qb_, aQ[i][j][3] + qb_);
      const unsigned k01 = cvtpk(aK[i][j][0] + kb_, aK[i][j][1] + kb_);
      const unsigned k23 = cvtpk(aK[i][j][2] + kb_, aK[i][j][3] + kb_);
      unsigned short* q_ = &Sq[(i * 16 + lq * 4) * 40 + j * 16 + l16];
      unsigned short* k_ = &Sk[(i * 16 + lq * 4) * 40 + j * 16 + l16];
      q_[0] = (unsigned short)q01;   q_[40] = (unsigned short)(q01 >> 16);
      q_[80] = (unsigned short)q23;  q_[120] = (unsigned short)(q23 >> 16);
      k_[0] = (unsigned short)k01;   k_[40] = (unsigned short)(k01 >> 16);
      k_[80] = (unsigned short)k23;  k_[120] = (unsigned short)(k23 >> 16);
    }
  // --- output row pointers (head-independent) ---
  unsigned short* ob[8];
  int rsw[8];
#pragma unroll
  for (int lt = 0; lt < 2; ++lt)
#pragma unroll
    for (int r = 0; r < 4; ++r) {
      const int l = lt * 16 + lq * 4 + r;
      const size_t rg = (size_t)l * (B_ * N_) + c;
      ob[lt * 4 + r] = oimg + (rg >> 7) * 16384 + (size_t)(rg & 127) * 128;
      rsw[lt * 4 + r] = (int)(rg & 7);
    }

  const float CSC = 0.25f * 1.4426950408889634f;  // qk scale * log2(e)
#pragma unroll
  for (int hh = 0; hh < 2; ++hh) {
    const int h = wv * 2 + hh;
    // ---- K A-frags / Q B-frags from scratch; k-slots lq>=2 stay zero ----
    short8 ka0 = {}, ka1 = {}, qb0 = {}, qb1 = {};
    if (lq < 2) {
      const int go = (2 * hh + lq) * 8;
      ka0 = *(const short8*)&Sk[l16 * 40 + go];
      ka1 = *(const short8*)&Sk[(16 + l16) * 40 + go];
      qb0 = *(const short8*)&Sq[l16 * 40 + go];
      qb1 = *(const short8*)&Sq[(16 + l16) * 40 + go];
    }
    // ---- S^T = K . Q^T : D row = m_local (lq*4+reg), col = l_local ----
    floatx4 st00 = {}, st01 = {}, st10 = {}, st11 = {};
    st00 = __builtin_amdgcn_mfma_f32_16x16x32_bf16(ka0, qb0, st00, 0, 0, 0);
    st01 = __builtin_amdgcn_mfma_f32_16x16x32_bf16(ka0, qb1, st01, 0, 0, 0);
    st10 = __builtin_amdgcn_mfma_f32_16x16x32_bf16(ka1, qb0, st10, 0, 0, 0);
    st11 = __builtin_amdgcn_mfma_f32_16x16x32_bf16(ka1, qb1, st11, 0, 0, 0);
    // ---- V B-frag directly from proj accumulators (pi-pairing) ----
    const float bV = hh ? bV1 : bV0;
    B8 vu;
    vu.u[0] = cvtpk(aV[0][hh][0] + bV, aV[0][hh][1] + bV);
    vu.u[1] = cvtpk(aV[0][hh][2] + bV, aV[0][hh][3] + bV);
    vu.u[2] = cvtpk(aV[1][hh][0] + bV, aV[1][hh][1] + bV);
    vu.u[3] = cvtpk(aV[1][hh][2] + bV, aV[1][hh][3] + bV);
    const short8 vb = vu.s;
    // ---- softmax per l-column (log2-domain exp); P packed via cvt_pk ----
    short8 pa0, pa1;
    {  // lt = 0: scores from st00 (m 0..15) and st10 (m 16..31)
      floatx4 a = st00 * CSC, cc = st10 * CSC;
      float mx = fmaxf(fmaxf(fmaxf(a[0], a[1]), fmaxf(a[2], a[3])),
                       fmaxf(fmaxf(cc[0], cc[1]), fmaxf(cc[2], cc[3])));
      mx = fmaxf(mx, __shfl_xor(mx, 16));
      mx = fmaxf(mx, __shfl_xor(mx, 32));
      float p0 = vexp2(a[0] - mx), p1 = vexp2(a[1] - mx);
      float p2 = vexp2(a[2] - mx), p3 = vexp2(a[3] - mx);
      float p4 = vexp2(cc[0] - mx), p5 = vexp2(cc[1] - mx);
      float p6 = vexp2(cc[2] - mx), p7 = vexp2(cc[3] - mx);
      float sm = ((p0 + p1) + (p2 + p3)) + ((p4 + p5) + (p6 + p7));
      sm += __shfl_xor(sm, 16);
      sm += __shfl_xor(sm, 32);
      const float inv = vrcp(sm);
      B8 pu;
      pu.u[0] = cvtpk(p0 * inv, p1 * inv);
      pu.u[1] = cvtpk(p2 * inv, p3 * inv);
      pu.u[2] = cvtpk(p4 * inv, p5 * inv);
      pu.u[3] = cvtpk(p6 * inv, p7 * inv);
      pa0 = pu.s;
    }
    {  // lt = 1: scores from st01 and st11
      floatx4 a = st01 * CSC, cc = st11 * CSC;
      float mx = fmaxf(fmaxf(fmaxf(a[0], a[1]), fmaxf(a[2], a[3])),
                       fmaxf(fmaxf(cc[0], cc[1]), fmaxf(cc[2], cc[3])));
      mx = fmaxf(mx, __shfl_xor(mx, 16));
      mx = fmaxf(mx, __shfl_xor(mx, 32));
      float p0 = vexp2(a[0] - mx), p1 = vexp2(a[1] - mx);
      float p2 = vexp2(a[2] - mx), p3 = vexp2(a[3] - mx);
      float p4 = vexp2(cc[0] - mx), p5 = vexp2(cc[1] - mx);
      float p6 = vexp2(cc[2] - mx), p7 = vexp2(cc[3] - mx);
      float sm = ((p0 + p1) + (p2 + p3)) + ((p4 + p5) + (p6 + p7));
      sm += __shfl_xor(sm, 16);
      sm += __shfl_xor(sm, 32);
      const float inv = vrcp(sm);
      B8 pu;
      pu.u[0] = cvtpk(p0 * inv, p1 * inv);
      pu.u[1] = cvtpk(p2 * inv, p3 * inv);
      pu.u[2] = cvtpk(p4 * inv, p5 * inv);
      pu.u[3] = cvtpk(p6 * inv, p7 * inv);
      pa1 = pu.s;
    }
    // ---- O = P.V : D row = l_local (lq*4+reg), col = d_local (l16) ----
    floatx4 o0 = {}, o1 = {};
    o0 = __builtin_amdgcn_mfma_f32_16x16x32_bf16(pa0, vb, o0, 0, 0, 0);
    o1 = __builtin_amdgcn_mfma_f32_16x16x32_bf16(pa1, vb, o1, 0, 0, 0);
    // ---- store this head's d-slice (d = h*16 + l16) into o_t image ----
    const int d = h * 16 + l16;
    const int gd = d >> 3, de = d & 7;
#pragma unroll
    for (int r = 0; r < 4; ++r) {
      const unsigned w = cvtpk(o0[r], o1[r]);
      ob[r][(gd ^ rsw[r]) * 8 + de] = (unsigned short)w;
      ob[4 + r][(gd ^ rsw[4 + r]) * 8 + de] = (unsigned short)(w >> 16);
    }
  }
}

// ---------------------------------------------------------------------------
// sattn_final (R12): spatial attention + output GEMM fused. One block per
// 128 consecutive global rows (bm), 512 threads (8 waves).
// Phase A (gather): each thread computes o_s for 2 (row,head) units — code
// identical to the proven sattn kernel — and writes the bf16 result into
// the Os LDS tile in image layout (same swizzled addressing the global
// store used; tile-aligned so rl = gr&127, sw = rl&7). Ws (s_out) is
// DMA'd into Bs at kernel entry, hidden under the gather.
// Phase B: acc = Os@Ws^T; restage Os<-o_t tile, Bs<-Wt; acc += o_t@Wt^T;
// epilogue out = acc + bt + bs. 64KB LDS -> 2 blocks/CU.
// Saves the o_s global round-trip (66 MB) and one kernel launch.
// ---------------------------------------------------------------------------
__global__ __launch_bounds__(512) void sattn_final(
    const unsigned short* __restrict__ qkv, const int* __restrict__ route,
    const unsigned short* __restrict__ otimg,
    const unsigned short* __restrict__ wtimg,  // t_out image slab
    const unsigned short* __restrict__ wsimg,  // s_out image slab
    const float* __restrict__ bt, const float* __restrict__ bs,
    float* __restrict__ out) {
  __shared__ unsigned short Os[128 * 128];  // o_s image tile; later o_t tile
  __shared__ unsigned short Bs[128 * 128];  // Ws; later Wt
  const int t = threadIdx.x;
  const int bm = blockIdx.x;
  // --- stage Ws early (independent of gather; hidden under phase A) ---
#pragma unroll
  for (int it = 0; it < 4; ++it) {
    int gi = it * 512 + t;
    gload_lds16(wsimg + (size_t)gi * 8, &Bs[gi * 8]);
  }
  // --- phase A: o_s for rows bm*128 .. +128 into Os (sattn body) ---
  const int h = t & 7;
#pragma unroll
  for (int it2 = 0; it2 < 2; ++it2) {
    const int rl = (t >> 3) + it2 * 64;       // 0..127
    const int gr = bm * 128 + rl;             // global row
    const int lb = (int)((unsigned)gr / 1000u);
    const int n = gr - lb * 1000;
    float q[16];
    {
      const unsigned short* qp = qkv + (size_t)gr * 384 + h * DH_;
      ushort8v q0 = *(const ushort8v*)qp;
      ushort8v q1 = *(const ushort8v*)(qp + 8);
#pragma unroll
      for (int i = 0; i < 8; ++i) { q[i] = bf2f(q0[i]); q[8 + i] = bf2f(q1[i]); }
    }
    int nb[KN_];
#pragma unroll
    for (int kk = 0; kk < KN_; ++kk) nb[kk] = route[n * KN_ + kk];
    // full preload: all k and v segments issued before any FMA
    ushort8v kr[KN_][2], vr[KN_][2];
#pragma unroll
    for (int kk = 0; kk < KN_; ++kk) {
      const unsigned short* base = qkv + ((size_t)lb * N_ + nb[kk]) * 384;
      const unsigned short* kp = base + 128 + h * DH_;
      const unsigned short* vp = base + 256 + h * DH_;
      kr[kk][0] = *(const ushort8v*)kp;
      kr[kk][1] = *(const ushort8v*)(kp + 8);
      vr[kk][0] = *(const ushort8v*)vp;
      vr[kk][1] = *(const ushort8v*)(vp + 8);
    }
    float sc[KN_];
    float mx = -1e30f;
#pragma unroll
    for (int kk = 0; kk < KN_; ++kk) {
      float d = 0.f;
#pragma unroll
      for (int i = 0; i < 8; ++i) {
        d = fmaf(q[i], bf2f(kr[kk][0][i]), d);
        d = fmaf(q[8 + i], bf2f(kr[kk][1][i]), d);
      }
      d *= 0.25f;
      sc[kk] = d;
      mx = fmaxf(mx, d);
    }
    float ssum = 0.f;
#pragma unroll
    for (int kk = 0; kk < KN_; ++kk) { sc[kk] = __expf(sc[kk] - mx); ssum += sc[kk]; }
    float inv = 1.f / ssum;
    float oa[16];
#pragma unroll
    for (int i = 0; i < 16; ++i) oa[i] = 0.f;
#pragma unroll
    for (int kk = 0; kk < KN_; ++kk) {
      float p = sc[kk] * inv;
#pragma unroll
      for (int i = 0; i < 8; ++i) {
        oa[i] = fmaf(p, bf2f(vr[kk][0][i]), oa[i]);
        oa[8 + i] = fmaf(p, bf2f(vr[kk][1][i]), oa[8 + i]);
      }
    }
    BW8 w0, w1;
    w0.u[0] = cvtpk(oa[0], oa[1]);   w0.u[1] = cvtpk(oa[2], oa[3]);
    w0.u[2] = cvtpk(oa[4], oa[5]);   w0.u[3] = cvtpk(oa[6], oa[7]);
    w1.u[0] = cvtpk(oa[8], oa[9]);   w1.u[1] = cvtpk(oa[10], oa[11]);
    w1.u[2] = cvtpk(oa[12], oa[13]); w1.u[3] = cvtpk(oa[14], oa[15]);
    const int sw = rl & 7;
    *(ushort8v*)(&Os[(size_t)(rl * 16 + ((2 * h) ^ sw)) * 8]) = w0.s;
    *(ushort8v*)(&Os[(size_t)(rl * 16 + ((2 * h + 1) ^ sw)) * 8]) = w1.s;
  }
  asm volatile("s_waitcnt vmcnt(0)" ::: "memory");
  __syncthreads();

  // --- phase B: two K=128 GEMM passes ---
  const int wave = t >> 6, lane = t & 63;
  const int wm = (wave >> 2) * 64, wn = (wave & 3) * 32;
  const int lq = lane >> 4, l16 = lane & 15;
  floatx4 acc[4][2] = {};
#pragma unroll
  for (int p = 0; p < 2; ++p) {
    if (p) {
      __syncthreads();  // all waves done reading Os/Bs
#pragma unroll
      for (int it = 0; it < 4; ++it) {
        int gi = it * 512 + t;
        gload_lds16(otimg + (size_t)bm * 16384 + (size_t)gi * 8, &Os[gi * 8]);
        gload_lds16(wtimg + (size_t)gi * 8, &Bs[gi * 8]);
      }
      asm volatile("s_waitcnt vmcnt(0)" ::: "memory");
      __syncthreads();
    }
#pragma unroll
    for (int kk = 0; kk < 4; ++kk) {
      int g = kk * 4 + lq;
      short8 a[4], b[2];
#pragma unroll
      for (int i = 0; i < 4; ++i) {
        int ma = wm + i * 16 + l16;
        a[i] = *(const short8*)(&Os[(ma * 16 + (g ^ (ma & 7))) * 8]);
      }
#pragma unroll
      for (int j = 0; j < 2; ++j) {
        int nb2 = wn + j * 16 + l16;
        b[j] = *(const short8*)(&Bs[(nb2 * 16 + (g ^ (nb2 & 7))) * 8]);
      }
#pragma unroll
      for (int i = 0; i < 4; ++i)
#pragma unroll
        for (int j = 0; j < 2; ++j)
          acc[i][j] = __builtin_amdgcn_mfma_f32_16x16x32_bf16(a[i], b[j],
                                                              acc[i][j], 0, 0, 0);
    }
  }
  const size_t rowBase = (size_t)bm * 128 + wm;
#pragma unroll
  for (int j = 0; j < 2; ++j) {
    int col = wn + j * 16 + l16;
    float bb = bt[col] + bs[col];
#pragma unroll
    for (int i = 0; i < 4; ++i) {
#pragma unroll
      for (int r = 0; r < 4; ++r) {
        size_t row = rowBase + i * 16 + lq * 4 + r;
        out[row * 128 + col] = acc[i][j][r] + bb;
      }
    }
  }
}

extern "C" void kernel_launch(void* const* d_in, const int* in_sizes, int n_in,
                              void* d_out, int out_size, void* d_ws,
                              size_t ws_size, hipStream_t stream) {
  const float* x = (const float*)d_in[0];
  const int* route = (const int*)d_in[1];
  const float* t_in_w = (const float*)d_in[2];
  const float* t_in_b = (const float*)d_in[3];
  const float* t_out_w = (const float*)d_in[4];
  const float* t_out_b = (const float*)d_in[5];
  const float* s_in_w = (const float*)d_in[6];
  const float* s_in_b = (const float*)d_in[7];
  const float* s_out_w = (const float*)d_in[8];
  const float* s_out_b = (const float*)d_in[9];
  float* out = (float*)d_out;
  // ws (ushorts): ximg [M*128] | qkv [M*384] | o_t img [M*128] | wimg [8*16384]
  unsigned short* ximg = (unsigned short*)d_ws;
  unsigned short* qkv = ximg + (size_t)M_ * 128;
  unsigned short* o_t = qkv + (size_t)M_ * 384;
  unsigned short* wimg = o_t + (size_t)M_ * 128;

  prep_kernel<<<1008, 256, 0, stream>>>(x, t_in_w, s_in_w, t_out_w, s_out_w,
                                        ximg, wimg);
  tattn_fused<<<B_ * N_, 256, 0, stream>>>(ximg, wimg, t_in_b, o_t);
  proj_mfma<<<(M_ / 128) * 3, 256, 0, stream>>>(ximg, wimg + 3 * 16384,
                                                s_in_b, qkv);
  sattn_final<<<M_ / 128, 512, 0, stream>>>(qkv, route, o_t,
                                            wimg + 6 * 16384, wimg + 7 * 16384,
                                            t_out_b, s_out_b, out);
}

// Round 7
// 257.788 us; speedup vs baseline: 1.1458x; 1.1458x over previous
//
#include <hip/hip_runtime.h>
#include <math.h>

#define L_ 32
#define B_ 4
#define N_ 1000
#define D_ 128
#define H_ 8
#define DH_ 16
#define KN_ 8
#define M_ (L_ * B_ * N_)  // 128000 rows

typedef __attribute__((ext_vector_type(8))) short short8;
typedef __attribute__((ext_vector_type(8))) unsigned short ushort8v;
typedef __attribute__((ext_vector_type(4))) float floatx4;
typedef __attribute__((ext_vector_type(4))) unsigned uintx4;

static __device__ __forceinline__ unsigned short f2bf(float f) {
  union { float f; unsigned u; } v; v.f = f;
  unsigned r = v.u + 0x7fffu + ((v.u >> 16) & 1u);
  return (unsigned short)(r >> 16);
}
static __device__ __forceinline__ float bf2f(unsigned short s) {
  union { unsigned u; float f; } v; v.u = ((unsigned)s) << 16;
  return v.f;
}
// packed 2xf32 -> 2xbf16 (RNE), 1 VALU inst
static __device__ __forceinline__ unsigned cvtpk(float lo, float hi) {
  unsigned r;
  asm("v_cvt_pk_bf16_f32 %0, %1, %2" : "=v"(r) : "v"(lo), "v"(hi));
  return r;
}
static __device__ __forceinline__ float vexp2(float x) {  // 2^x
  float r; asm("v_exp_f32 %0, %1" : "=v"(r) : "v"(x)); return r;
}
static __device__ __forceinline__ float vrcp(float x) {  // ~1ulp 1/x
  float r; asm("v_rcp_f32 %0, %1" : "=v"(r) : "v"(x)); return r;
}
union B8 { uintx4 u; short8 s; };
union BW8 { uintx4 u; ushort8v s; };
// async global->LDS, 16B per lane; LDS dest is wave-uniform base + lane*16.
static __device__ __forceinline__ void gload_lds16(const unsigned short* g,
                                                   unsigned short* l) {
  __builtin_amdgcn_global_load_lds(
      (const __attribute__((address_space(1))) unsigned int*)g,
      (__attribute__((address_space(3))) unsigned int*)l, 16, 0, 0);
}

// ---------------------------------------------------------------------------
// prep: fp32 -> bf16 128x128 tile-images in LDS byte order (XOR-swizzled
// 16B granules: granule g of row m lands at m*16 + (g^(m&7))).
// Blocks 0..999: x tiles. 1000..1007: weight tiles
// (0-2 t_in, 3-5 s_in, 6 t_out, 7 s_out).
// ---------------------------------------------------------------------------
__global__ __launch_bounds__(256) void prep_kernel(
    const float* __restrict__ x, const float* __restrict__ wt_in,
    const float* __restrict__ ws_in, const float* __restrict__ wt_out,
    const float* __restrict__ ws_out, unsigned short* __restrict__ ximg,
    unsigned short* __restrict__ wimg) {
  const int bid = blockIdx.x, t = threadIdx.x;
  const float* src;
  unsigned short* dst;
  if (bid < 1000) {
    src = x + (size_t)bid * 16384;
    dst = ximg + (size_t)bid * 16384;
  } else {
    int w = bid - 1000;
    if (w < 3) src = wt_in + (size_t)w * 16384;
    else if (w < 6) src = ws_in + (size_t)(w - 3) * 16384;
    else if (w == 6) src = wt_out;
    else src = ws_out;
    dst = wimg + (size_t)w * 16384;
  }
#pragma unroll
  for (int it = 0; it < 8; ++it) {
    int gi = it * 256 + t;  // 0..2047
    int m = gi >> 4, g = gi & 15;
    const float4* sp = (const float4*)(src + m * 128 + g * 8);
    float4 a = sp[0], b = sp[1];
    ushort8v o;
    o[0] = f2bf(a.x); o[1] = f2bf(a.y); o[2] = f2bf(a.z); o[3] = f2bf(a.w);
    o[4] = f2bf(b.x); o[5] = f2bf(b.y); o[6] = f2bf(b.z); o[7] = f2bf(b.w);
    *(ushort8v*)(dst + (size_t)(m * 16 + (g ^ (m & 7))) * 8) = o;
  }
}

// ---------------------------------------------------------------------------
// proj_mfma: qkv(M,384) bf16 = x @ W^T + bias. Pure-DMA staging of
// pre-swizzled images; 128x128 tile; 4x4 grid of 16x16x32 bf16 MFMAs/wave.
// (used only for the spatial path)
// ---------------------------------------------------------------------------
__global__ __launch_bounds__(256) void proj_mfma(
    const unsigned short* __restrict__ ximg,
    const unsigned short* __restrict__ wimg, const float* __restrict__ bias,
    unsigned short* __restrict__ out) {
  __shared__ unsigned short As[128 * 128];
  __shared__ unsigned short Bs[128 * 128];
  const int t = threadIdx.x;
  const int bm = blockIdx.x / 3, bn = blockIdx.x % 3;
  const unsigned short* aSrc = ximg + (size_t)bm * 16384;
  const unsigned short* bSrc = wimg + (size_t)bn * 16384;
#pragma unroll
  for (int it = 0; it < 8; ++it) {
    int gi = it * 256 + t;
    gload_lds16(aSrc + (size_t)gi * 8, &As[gi * 8]);
    gload_lds16(bSrc + (size_t)gi * 8, &Bs[gi * 8]);
  }
  __syncthreads();
  const int wave = t >> 6, lane = t & 63;
  const int wm = (wave >> 1) * 64, wn = (wave & 1) * 64;
  const int lq = lane >> 4, l16 = lane & 15;
  floatx4 acc[4][4] = {};
#pragma unroll
  for (int kk = 0; kk < 4; ++kk) {
    int g = kk * 4 + lq;
    short8 a[4], b[4];
#pragma unroll
    for (int i = 0; i < 4; ++i) {
      int ma = wm + i * 16 + l16;
      a[i] = *(const short8*)(&As[(ma * 16 + (g ^ (ma & 7))) * 8]);
      int nb = wn + i * 16 + l16;
      b[i] = *(const short8*)(&Bs[(nb * 16 + (g ^ (nb & 7))) * 8]);
    }
#pragma unroll
    for (int i = 0; i < 4; ++i)
#pragma unroll
      for (int j = 0; j < 4; ++j)
        acc[i][j] = __builtin_amdgcn_mfma_f32_16x16x32_bf16(a[i], b[j],
                                                            acc[i][j], 0, 0, 0);
  }
  const size_t rowBase = (size_t)bm * 128 + wm;
  const int colBase = bn * 128 + wn;
#pragma unroll
  for (int j = 0; j < 4; ++j) {
    float bb = bias[colBase + j * 16 + l16];
#pragma unroll
    for (int i = 0; i < 4; ++i) {
#pragma unroll
      for (int r = 0; r < 4; ++r) {
        size_t row = rowBase + i * 16 + lq * 4 + r;
        out[row * 384 + colBase + j * 16 + l16] = f2bf(acc[i][j][r] + bb);
      }
    }
  }
}

// ---------------------------------------------------------------------------
// tattn_fused (R11, unchanged): projection + temporal attention.
// One block per (b,n), 4 waves; wave w owns heads 2w,2w+1. bf16 packing via
// v_cvt_pk_bf16_f32; exp via v_exp_f32 (log2-domain); 1/sum via v_rcp_f32.
// V stays in registers (pi-pairing); Q,K transposed through 32x40 LDS.
// ---------------------------------------------------------------------------
__global__ __launch_bounds__(256) void tattn_fused(
    const unsigned short* __restrict__ ximg,
    const unsigned short* __restrict__ wimg,  // t_in slabs 0..2
    const float* __restrict__ bias,           // t_in_b[384]
    unsigned short* __restrict__ oimg) {
  __shared__ unsigned short Sx[512 * 8];         // 8KB: x rows 0..31
  __shared__ unsigned short Sqk[4][2][32 * 40];  // 20KB: per-wave Q,K scratch
  const int t = threadIdx.x;
  const int b = blockIdx.x / N_;
  const int n = blockIdx.x % N_;
  const int c = b * N_ + n;
  // --- stage x rows l=0..31 (global row rg = l*4000 + c) ---
#pragma unroll
  for (int it = 0; it < 2; ++it) {
    const int s = it * 256 + t;
    const int ml = s >> 4, gs = s & 15;
    const int G = gs ^ (ml & 7);  // dest slot gs holds granule G
    const size_t rg = (size_t)ml * (B_ * N_) + c;
    gload_lds16(ximg + (rg >> 7) * 16384 +
                    ((rg & 127) * 16 + (size_t)(G ^ ((int)rg & 7))) * 8,
                &Sx[s * 8]);
  }
  asm volatile("s_waitcnt vmcnt(0)" ::: "memory");
  __syncthreads();

  const int wv = t >> 6, lane = t & 63;
  const int lq = lane >> 4, l16 = lane & 15;

  // --- projection: Q,K,V (32 rows x 32 cols) for this wave's head pair ---
  floatx4 aQ[2][2] = {}, aK[2][2] = {}, aV[2][2] = {};
#pragma unroll
  for (int kk = 0; kk < 4; ++kk) {
    short8 a[2];
#pragma unroll
    for (int i = 0; i < 2; ++i) {
      const int ml = i * 16 + l16;
      a[i] = *(const short8*)&Sx[(ml * 16 + ((kk * 4 + lq) ^ (ml & 7))) * 8];
    }
#pragma unroll
    for (int mat = 0; mat < 3; ++mat) {
      const unsigned short* wb = wimg + mat * 16384;
      short8 bf[2];
#pragma unroll
      for (int j = 0; j < 2; ++j) {
        const int nb = wv * 32 + j * 16 + l16;
        bf[j] =
            *(const short8*)&wb[(nb * 16 + ((kk * 4 + lq) ^ (nb & 7))) * 8];
      }
#pragma unroll
      for (int i = 0; i < 2; ++i)
#pragma unroll
        for (int j = 0; j < 2; ++j) {
          floatx4* acc = mat == 0 ? &aQ[i][j] : (mat == 1 ? &aK[i][j] : &aV[i][j]);
          *acc = __builtin_amdgcn_mfma_f32_16x16x32_bf16(a[i], bf[j], *acc, 0,
                                                         0, 0);
        }
    }
  }
  // --- bias + write Q,K to per-wave scratch (cvt_pk, rows stride 40) ---
  const float bQ0 = bias[wv * 32 + l16], bQ1 = bias[wv * 32 + 16 + l16];
  const float bK0 = bias[128 + wv * 32 + l16],
              bK1 = bias[128 + wv * 32 + 16 + l16];
  const float bV0 = bias[256 + wv * 32 + l16],
              bV1 = bias[256 + wv * 32 + 16 + l16];
  unsigned short* Sq = Sqk[wv][0];
  unsigned short* Sk = Sqk[wv][1];
#pragma unroll
  for (int i = 0; i < 2; ++i)
#pragma unroll
    for (int j = 0; j < 2; ++j) {
      const float qb_ = j ? bQ1 : bQ0, kb_ = j ? bK1 : bK0;
      const unsigned q01 = cvtpk(aQ[i][j][0] + qb_, aQ[i][j][1] + qb_);
      const unsigned q23 = cvtpk(aQ[i][j][2] + qb_, aQ[i][j][3] + qb_);
      const unsigned k01 = cvtpk(aK[i][j][0] + kb_, aK[i][j][1] + kb_);
      const unsigned k23 = cvtpk(aK[i][j][2] + kb_, aK[i][j][3] + kb_);
      unsigned short* q_ = &Sq[(i * 16 + lq * 4) * 40 + j * 16 + l16];
      unsigned short* k_ = &Sk[(i * 16 + lq * 4) * 40 + j * 16 + l16];
      q_[0] = (unsigned short)q01;   q_[40] = (unsigned short)(q01 >> 16);
      q_[80] = (unsigned short)q23;  q_[120] = (unsigned short)(q23 >> 16);
      k_[0] = (unsigned short)k01;   k_[40] = (unsigned short)(k01 >> 16);
      k_[80] = (unsigned short)k23;  k_[120] = (unsigned short)(k23 >> 16);
    }
  // --- output row pointers (head-independent) ---
  unsigned short* ob[8];
  int rsw[8];
#pragma unroll
  for (int lt = 0; lt < 2; ++lt)
#pragma unroll
    for (int r = 0; r < 4; ++r) {
      const int l = lt * 16 + lq * 4 + r;
      const size_t rg = (size_t)l * (B_ * N_) + c;
      ob[lt * 4 + r] = oimg + (rg >> 7) * 16384 + (size_t)(rg & 127) * 128;
      rsw[lt * 4 + r] = (int)(rg & 7);
    }

  const float CSC = 0.25f * 1.4426950408889634f;  // qk scale * log2(e)
#pragma unroll
  for (int hh = 0; hh < 2; ++hh) {
    const int h = wv * 2 + hh;
    // ---- K A-frags / Q B-frags from scratch; k-slots lq>=2 stay zero ----
    short8 ka0 = {}, ka1 = {}, qb0 = {}, qb1 = {};
    if (lq < 2) {
      const int go = (2 * hh + lq) * 8;
      ka0 = *(const short8*)&Sk[l16 * 40 + go];
      ka1 = *(const short8*)&Sk[(16 + l16) * 40 + go];
      qb0 = *(const short8*)&Sq[l16 * 40 + go];
      qb1 = *(const short8*)&Sq[(16 + l16) * 40 + go];
    }
    // ---- S^T = K . Q^T : D row = m_local (lq*4+reg), col = l_local ----
    floatx4 st00 = {}, st01 = {}, st10 = {}, st11 = {};
    st00 = __builtin_amdgcn_mfma_f32_16x16x32_bf16(ka0, qb0, st00, 0, 0, 0);
    st01 = __builtin_amdgcn_mfma_f32_16x16x32_bf16(ka0, qb1, st01, 0, 0, 0);
    st10 = __builtin_amdgcn_mfma_f32_16x16x32_bf16(ka1, qb0, st10, 0, 0, 0);
    st11 = __builtin_amdgcn_mfma_f32_16x16x32_bf16(ka1, qb1, st11, 0, 0, 0);
    // ---- V B-frag directly from proj accumulators (pi-pairing) ----
    const float bV = hh ? bV1 : bV0;
    B8 vu;
    vu.u[0] = cvtpk(aV[0][hh][0] + bV, aV[0][hh][1] + bV);
    vu.u[1] = cvtpk(aV[0][hh][2] + bV, aV[0][hh][3] + bV);
    vu.u[2] = cvtpk(aV[1][hh][0] + bV, aV[1][hh][1] + bV);
    vu.u[3] = cvtpk(aV[1][hh][2] + bV, aV[1][hh][3] + bV);
    const short8 vb = vu.s;
    // ---- softmax per l-column (log2-domain exp); P packed via cvt_pk ----
    short8 pa0, pa1;
    {  // lt = 0: scores from st00 (m 0..15) and st10 (m 16..31)
      floatx4 a = st00 * CSC, cc = st10 * CSC;
      float mx = fmaxf(fmaxf(fmaxf(a[0], a[1]), fmaxf(a[2], a[3])),
                       fmaxf(fmaxf(cc[0], cc[1]), fmaxf(cc[2], cc[3])));
      mx = fmaxf(mx, __shfl_xor(mx, 16));
      mx = fmaxf(mx, __shfl_xor(mx, 32));
      float p0 = vexp2(a[0] - mx), p1 = vexp2(a[1] - mx);
      float p2 = vexp2(a[2] - mx), p3 = vexp2(a[3] - mx);
      float p4 = vexp2(cc[0] - mx), p5 = vexp2(cc[1] - mx);
      float p6 = vexp2(cc[2] - mx), p7 = vexp2(cc[3] - mx);
      float sm = ((p0 + p1) + (p2 + p3)) + ((p4 + p5) + (p6 + p7));
      sm += __shfl_xor(sm, 16);
      sm += __shfl_xor(sm, 32);
      const float inv = vrcp(sm);
      B8 pu;
      pu.u[0] = cvtpk(p0 * inv, p1 * inv);
      pu.u[1] = cvtpk(p2 * inv, p3 * inv);
      pu.u[2] = cvtpk(p4 * inv, p5 * inv);
      pu.u[3] = cvtpk(p6 * inv, p7 * inv);
      pa0 = pu.s;
    }
    {  // lt = 1: scores from st01 and st11
      floatx4 a = st01 * CSC, cc = st11 * CSC;
      float mx = fmaxf(fmaxf(fmaxf(a[0], a[1]), fmaxf(a[2], a[3])),
                       fmaxf(fmaxf(cc[0], cc[1]), fmaxf(cc[2], cc[3])));
      mx = fmaxf(mx, __shfl_xor(mx, 16));
      mx = fmaxf(mx, __shfl_xor(mx, 32));
      float p0 = vexp2(a[0] - mx), p1 = vexp2(a[1] - mx);
      float p2 = vexp2(a[2] - mx), p3 = vexp2(a[3] - mx);
      float p4 = vexp2(cc[0] - mx), p5 = vexp2(cc[1] - mx);
      float p6 = vexp2(cc[2] - mx), p7 = vexp2(cc[3] - mx);
      float sm = ((p0 + p1) + (p2 + p3)) + ((p4 + p5) + (p6 + p7));
      sm += __shfl_xor(sm, 16);
      sm += __shfl_xor(sm, 32);
      const float inv = vrcp(sm);
      B8 pu;
      pu.u[0] = cvtpk(p0 * inv, p1 * inv);
      pu.u[1] = cvtpk(p2 * inv, p3 * inv);
      pu.u[2] = cvtpk(p4 * inv, p5 * inv);
      pu.u[3] = cvtpk(p6 * inv, p7 * inv);
      pa1 = pu.s;
    }
    // ---- O = P.V : D row = l_local (lq*4+reg), col = d_local (l16) ----
    floatx4 o0 = {}, o1 = {};
    o0 = __builtin_amdgcn_mfma_f32_16x16x32_bf16(pa0, vb, o0, 0, 0, 0);
    o1 = __builtin_amdgcn_mfma_f32_16x16x32_bf16(pa1, vb, o1, 0, 0, 0);
    // ---- store this head's d-slice (d = h*16 + l16) into o_t image ----
    const int d = h * 16 + l16;
    const int gd = d >> 3, de = d & 7;
#pragma unroll
    for (int r = 0; r < 4; ++r) {
      const unsigned w = cvtpk(o0[r], o1[r]);
      ob[r][(gd ^ rsw[r]) * 8 + de] = (unsigned short)w;
      ob[4 + r][(gd ^ rsw[4 + r]) * 8 + de] = (unsigned short)(w >> 16);
    }
  }
}

// ---------------------------------------------------------------------------
// sattn_final (R13): spatial attention + output GEMM fused, XCD-pinned.
// R5 lesson: bm = blockIdx broke R7's slab pinning -> every 512KB gather
// slab fetched by 8 XCDs (FETCH 248MB, 85us). Fix: bijective remap
// bm = (bb&7)*125 + (bb>>3) — hw XCD bb%8 owns bm in [125x,125x+125) →
// slabs [16x,16x+16), so a slab's ~8 blocks share one L2 and each XCD
// walks its slabs sequentially (~8 hot slabs x 512KB ≈ L2 size).
// Phase A: gather o_s for 128 consecutive rows into the Os LDS tile
// (image layout, tile-aligned). Ws staged at entry (hidden under gather).
// Phase B: acc = Os@Ws^T; restage o_t/Wt; acc += o_t@Wt^T; out=acc+bt+bs.
// ---------------------------------------------------------------------------
__global__ __launch_bounds__(512) void sattn_final(
    const unsigned short* __restrict__ qkv, const int* __restrict__ route,
    const unsigned short* __restrict__ otimg,
    const unsigned short* __restrict__ wtimg,  // t_out image slab
    const unsigned short* __restrict__ wsimg,  // s_out image slab
    const float* __restrict__ bt, const float* __restrict__ bs,
    float* __restrict__ out) {
  __shared__ unsigned short Os[128 * 128];  // o_s image tile; later o_t tile
  __shared__ unsigned short Bs[128 * 128];  // Ws; later Wt
  const int t = threadIdx.x;
  const int bb = blockIdx.x;
  const int bm = (bb & 7) * 125 + (bb >> 3);  // XCD-pinned tile order
  // --- stage Ws early (independent of gather; hidden under phase A) ---
#pragma unroll
  for (int it = 0; it < 4; ++it) {
    int gi = it * 512 + t;
    gload_lds16(wsimg + (size_t)gi * 8, &Bs[gi * 8]);
  }
  // --- phase A: o_s for rows bm*128 .. +128 into Os (sattn body) ---
  const int h = t & 7;
#pragma unroll
  for (int it2 = 0; it2 < 2; ++it2) {
    const int rl = (t >> 3) + it2 * 64;       // 0..127
    const int gr = bm * 128 + rl;             // global row
    const int lb = (int)((unsigned)gr / 1000u);
    const int n = gr - lb * 1000;
    float q[16];
    {
      const unsigned short* qp = qkv + (size_t)gr * 384 + h * DH_;
      ushort8v q0 = *(const ushort8v*)qp;
      ushort8v q1 = *(const ushort8v*)(qp + 8);
#pragma unroll
      for (int i = 0; i < 8; ++i) { q[i] = bf2f(q0[i]); q[8 + i] = bf2f(q1[i]); }
    }
    int nb[KN_];
#pragma unroll
    for (int kk = 0; kk < KN_; ++kk) nb[kk] = route[n * KN_ + kk];
    // full preload: all k and v segments issued before any FMA
    ushort8v kr[KN_][2], vr[KN_][2];
#pragma unroll
    for (int kk = 0; kk < KN_; ++kk) {
      const unsigned short* base = qkv + ((size_t)lb * N_ + nb[kk]) * 384;
      const unsigned short* kp = base + 128 + h * DH_;
      const unsigned short* vp = base + 256 + h * DH_;
      kr[kk][0] = *(const ushort8v*)kp;
      kr[kk][1] = *(const ushort8v*)(kp + 8);
      vr[kk][0] = *(const ushort8v*)vp;
      vr[kk][1] = *(const ushort8v*)(vp + 8);
    }
    float sc[KN_];
    float mx = -1e30f;
#pragma unroll
    for (int kk = 0; kk < KN_; ++kk) {
      float d = 0.f;
#pragma unroll
      for (int i = 0; i < 8; ++i) {
        d = fmaf(q[i], bf2f(kr[kk][0][i]), d);
        d = fmaf(q[8 + i], bf2f(kr[kk][1][i]), d);
      }
      d *= 0.25f;
      sc[kk] = d;
      mx = fmaxf(mx, d);
    }
    float ssum = 0.f;
#pragma unroll
    for (int kk = 0; kk < KN_; ++kk) { sc[kk] = __expf(sc[kk] - mx); ssum += sc[kk]; }
    float inv = 1.f / ssum;
    float oa[16];
#pragma unroll
    for (int i = 0; i < 16; ++i) oa[i] = 0.f;
#pragma unroll
    for (int kk = 0; kk < KN_; ++kk) {
      float p = sc[kk] * inv;
#pragma unroll
      for (int i = 0; i < 8; ++i) {
        oa[i] = fmaf(p, bf2f(vr[kk][0][i]), oa[i]);
        oa[8 + i] = fmaf(p, bf2f(vr[kk][1][i]), oa[8 + i]);
      }
    }
    BW8 w0, w1;
    w0.u[0] = cvtpk(oa[0], oa[1]);   w0.u[1] = cvtpk(oa[2], oa[3]);
    w0.u[2] = cvtpk(oa[4], oa[5]);   w0.u[3] = cvtpk(oa[6], oa[7]);
    w1.u[0] = cvtpk(oa[8], oa[9]);   w1.u[1] = cvtpk(oa[10], oa[11]);
    w1.u[2] = cvtpk(oa[12], oa[13]); w1.u[3] = cvtpk(oa[14], oa[15]);
    const int sw = rl & 7;
    *(ushort8v*)(&Os[(size_t)(rl * 16 + ((2 * h) ^ sw)) * 8]) = w0.s;
    *(ushort8v*)(&Os[(size_t)(rl * 16 + ((2 * h + 1) ^ sw)) * 8]) = w1.s;
  }
  asm volatile("s_waitcnt vmcnt(0)" ::: "memory");
  __syncthreads();

  // --- phase B: two K=128 GEMM passes ---
  const int wave = t >> 6, lane = t & 63;
  const int wm = (wave >> 2) * 64, wn = (wave & 3) * 32;
  const int lq = lane >> 4, l16 = lane & 15;
  floatx4 acc[4][2] = {};
#pragma unroll
  for (int p = 0; p < 2; ++p) {
    if (p) {
      __syncthreads();  // all waves done reading Os/Bs
#pragma unroll
      for (int it = 0; it < 4; ++it) {
        int gi = it * 512 + t;
        gload_lds16(otimg + (size_t)bm * 16384 + (size_t)gi * 8, &Os[gi * 8]);
        gload_lds16(wtimg + (size_t)gi * 8, &Bs[gi * 8]);
      }
      asm volatile("s_waitcnt vmcnt(0)" ::: "memory");
      __syncthreads();
    }
#pragma unroll
    for (int kk = 0; kk < 4; ++kk) {
      int g = kk * 4 + lq;
      short8 a[4], b[2];
#pragma unroll
      for (int i = 0; i < 4; ++i) {
        int ma = wm + i * 16 + l16;
        a[i] = *(const short8*)(&Os[(ma * 16 + (g ^ (ma & 7))) * 8]);
      }
#pragma unroll
      for (int j = 0; j < 2; ++j) {
        int nb2 = wn + j * 16 + l16;
        b[j] = *(const short8*)(&Bs[(nb2 * 16 + (g ^ (nb2 & 7))) * 8]);
      }
#pragma unroll
      for (int i = 0; i < 4; ++i)
#pragma unroll
        for (int j = 0; j < 2; ++j)
          acc[i][j] = __builtin_amdgcn_mfma_f32_16x16x32_bf16(a[i], b[j],
                                                              acc[i][j], 0, 0, 0);
    }
  }
  const size_t rowBase = (size_t)bm * 128 + wm;
#pragma unroll
  for (int j = 0; j < 2; ++j) {
    int col = wn + j * 16 + l16;
    float bb2 = bt[col] + bs[col];
#pragma unroll
    for (int i = 0; i < 4; ++i) {
#pragma unroll
      for (int r = 0; r < 4; ++r) {
        size_t row = rowBase + i * 16 + lq * 4 + r;
        out[row * 128 + col] = acc[i][j][r] + bb2;
      }
    }
  }
}

extern "C" void kernel_launch(void* const* d_in, const int* in_sizes, int n_in,
                              void* d_out, int out_size, void* d_ws,
                              size_t ws_size, hipStream_t stream) {
  const float* x = (const float*)d_in[0];
  const int* route = (const int*)d_in[1];
  const float* t_in_w = (const float*)d_in[2];
  const float* t_in_b = (const float*)d_in[3];
  const float* t_out_w = (const float*)d_in[4];
  const float* t_out_b = (const float*)d_in[5];
  const float* s_in_w = (const float*)d_in[6];
  const float* s_in_b = (const float*)d_in[7];
  const float* s_out_w = (const float*)d_in[8];
  const float* s_out_b = (const float*)d_in[9];
  float* out = (float*)d_out;
  // ws (ushorts): ximg [M*128] | qkv [M*384] | o_t img [M*128] | wimg [8*16384]
  unsigned short* ximg = (unsigned short*)d_ws;
  unsigned short* qkv = ximg + (size_t)M_ * 128;
  unsigned short* o_t = qkv + (size_t)M_ * 384;
  unsigned short* wimg = o_t + (size_t)M_ * 128;

  prep_kernel<<<1008, 256, 0, stream>>>(x, t_in_w, s_in_w, t_out_w, s_out_w,
                                        ximg, wimg);
  tattn_fused<<<B_ * N_, 256, 0, stream>>>(ximg, wimg, t_in_b, o_t);
  proj_mfma<<<(M_ / 128) * 3, 256, 0, stream>>>(ximg, wimg + 3 * 16384,
                                                s_in_b, qkv);
  sattn_final<<<M_ / 128, 512, 0, stream>>>(qkv, route, o_t,
                                            wimg + 6 * 16384, wimg + 7 * 16384,
                                            t_out_b, s_out_b, out);
}

// Round 8
// 257.623 us; speedup vs baseline: 1.1465x; 1.0006x over previous
//
#include <hip/hip_runtime.h>
#include <math.h>

#define L_ 32
#define B_ 4
#define N_ 1000
#define D_ 128
#define H_ 8
#define DH_ 16
#define KN_ 8
#define M_ (L_ * B_ * N_)  // 128000 rows

typedef __attribute__((ext_vector_type(8))) short short8;
typedef __attribute__((ext_vector_type(8))) unsigned short ushort8v;
typedef __attribute__((ext_vector_type(4))) float floatx4;
typedef __attribute__((ext_vector_type(4))) unsigned uintx4;

static __device__ __forceinline__ unsigned short f2bf(float f) {
  union { float f; unsigned u; } v; v.f = f;
  unsigned r = v.u + 0x7fffu + ((v.u >> 16) & 1u);
  return (unsigned short)(r >> 16);
}
static __device__ __forceinline__ float bf2f(unsigned short s) {
  union { unsigned u; float f; } v; v.u = ((unsigned)s) << 16;
  return v.f;
}
// packed 2xf32 -> 2xbf16 (RNE), 1 VALU inst
static __device__ __forceinline__ unsigned cvtpk(float lo, float hi) {
  unsigned r;
  asm("v_cvt_pk_bf16_f32 %0, %1, %2" : "=v"(r) : "v"(lo), "v"(hi));
  return r;
}
static __device__ __forceinline__ float vexp2(float x) {  // 2^x
  float r; asm("v_exp_f32 %0, %1" : "=v"(r) : "v"(x)); return r;
}
static __device__ __forceinline__ float vrcp(float x) {  // ~1ulp 1/x
  float r; asm("v_rcp_f32 %0, %1" : "=v"(r) : "v"(x)); return r;
}
union B8 { uintx4 u; short8 s; };
union BW8 { uintx4 u; ushort8v s; };
// async global->LDS, 16B per lane; LDS dest is wave-uniform base + lane*16.
static __device__ __forceinline__ void gload_lds16(const unsigned short* g,
                                                   unsigned short* l) {
  __builtin_amdgcn_global_load_lds(
      (const __attribute__((address_space(1))) unsigned int*)g,
      (__attribute__((address_space(3))) unsigned int*)l, 16, 0, 0);
}

// ---------------------------------------------------------------------------
// prep: fp32 -> bf16 128x128 tile-images in LDS byte order (XOR-swizzled
// 16B granules: granule g of row m lands at m*16 + (g^(m&7))).
// Blocks 0..999: x tiles. 1000..1007: weight tiles
// (0-2 t_in, 3-5 s_in, 6 t_out, 7 s_out).
// ---------------------------------------------------------------------------
__global__ __launch_bounds__(256) void prep_kernel(
    const float* __restrict__ x, const float* __restrict__ wt_in,
    const float* __restrict__ ws_in, const float* __restrict__ wt_out,
    const float* __restrict__ ws_out, unsigned short* __restrict__ ximg,
    unsigned short* __restrict__ wimg) {
  const int bid = blockIdx.x, t = threadIdx.x;
  const float* src;
  unsigned short* dst;
  if (bid < 1000) {
    src = x + (size_t)bid * 16384;
    dst = ximg + (size_t)bid * 16384;
  } else {
    int w = bid - 1000;
    if (w < 3) src = wt_in + (size_t)w * 16384;
    else if (w < 6) src = ws_in + (size_t)(w - 3) * 16384;
    else if (w == 6) src = wt_out;
    else src = ws_out;
    dst = wimg + (size_t)w * 16384;
  }
#pragma unroll
  for (int it = 0; it < 8; ++it) {
    int gi = it * 256 + t;  // 0..2047
    int m = gi >> 4, g = gi & 15;
    const float4* sp = (const float4*)(src + m * 128 + g * 8);
    float4 a = sp[0], b = sp[1];
    ushort8v o;
    o[0] = f2bf(a.x); o[1] = f2bf(a.y); o[2] = f2bf(a.z); o[3] = f2bf(a.w);
    o[4] = f2bf(b.x); o[5] = f2bf(b.y); o[6] = f2bf(b.z); o[7] = f2bf(b.w);
    *(ushort8v*)(dst + (size_t)(m * 16 + (g ^ (m & 7))) * 8) = o;
  }
}

// ---------------------------------------------------------------------------
// proj_mfma: qkv(M,384) bf16 = x @ W^T + bias. Pure-DMA staging of
// pre-swizzled images; 128x128 tile; 4x4 grid of 16x16x32 bf16 MFMAs/wave.
// (used only for the spatial path)
// ---------------------------------------------------------------------------
__global__ __launch_bounds__(256) void proj_mfma(
    const unsigned short* __restrict__ ximg,
    const unsigned short* __restrict__ wimg, const float* __restrict__ bias,
    unsigned short* __restrict__ out) {
  __shared__ unsigned short As[128 * 128];
  __shared__ unsigned short Bs[128 * 128];
  const int t = threadIdx.x;
  const int bm = blockIdx.x / 3, bn = blockIdx.x % 3;
  const unsigned short* aSrc = ximg + (size_t)bm * 16384;
  const unsigned short* bSrc = wimg + (size_t)bn * 16384;
#pragma unroll
  for (int it = 0; it < 8; ++it) {
    int gi = it * 256 + t;
    gload_lds16(aSrc + (size_t)gi * 8, &As[gi * 8]);
    gload_lds16(bSrc + (size_t)gi * 8, &Bs[gi * 8]);
  }
  __syncthreads();
  const int wave = t >> 6, lane = t & 63;
  const int wm = (wave >> 1) * 64, wn = (wave & 1) * 64;
  const int lq = lane >> 4, l16 = lane & 15;
  floatx4 acc[4][4] = {};
#pragma unroll
  for (int kk = 0; kk < 4; ++kk) {
    int g = kk * 4 + lq;
    short8 a[4], b[4];
#pragma unroll
    for (int i = 0; i < 4; ++i) {
      int ma = wm + i * 16 + l16;
      a[i] = *(const short8*)(&As[(ma * 16 + (g ^ (ma & 7))) * 8]);
      int nb = wn + i * 16 + l16;
      b[i] = *(const short8*)(&Bs[(nb * 16 + (g ^ (nb & 7))) * 8]);
    }
#pragma unroll
    for (int i = 0; i < 4; ++i)
#pragma unroll
      for (int j = 0; j < 4; ++j)
        acc[i][j] = __builtin_amdgcn_mfma_f32_16x16x32_bf16(a[i], b[j],
                                                            acc[i][j], 0, 0, 0);
  }
  const size_t rowBase = (size_t)bm * 128 + wm;
  const int colBase = bn * 128 + wn;
#pragma unroll
  for (int j = 0; j < 4; ++j) {
    float bb = bias[colBase + j * 16 + l16];
#pragma unroll
    for (int i = 0; i < 4; ++i) {
#pragma unroll
      for (int r = 0; r < 4; ++r) {
        size_t row = rowBase + i * 16 + lq * 4 + r;
        out[row * 384 + colBase + j * 16 + l16] = f2bf(acc[i][j][r] + bb);
      }
    }
  }
}

// ---------------------------------------------------------------------------
// tattn_fused (R11, unchanged): projection + temporal attention.
// One block per (b,n), 4 waves; wave w owns heads 2w,2w+1. bf16 packing via
// v_cvt_pk_bf16_f32; exp via v_exp_f32 (log2-domain); 1/sum via v_rcp_f32.
// V stays in registers (pi-pairing); Q,K transposed through 32x40 LDS.
// ---------------------------------------------------------------------------
__global__ __launch_bounds__(256) void tattn_fused(
    const unsigned short* __restrict__ ximg,
    const unsigned short* __restrict__ wimg,  // t_in slabs 0..2
    const float* __restrict__ bias,           // t_in_b[384]
    unsigned short* __restrict__ oimg) {
  __shared__ unsigned short Sx[512 * 8];         // 8KB: x rows 0..31
  __shared__ unsigned short Sqk[4][2][32 * 40];  // 20KB: per-wave Q,K scratch
  const int t = threadIdx.x;
  const int b = blockIdx.x / N_;
  const int n = blockIdx.x % N_;
  const int c = b * N_ + n;
  // --- stage x rows l=0..31 (global row rg = l*4000 + c) ---
#pragma unroll
  for (int it = 0; it < 2; ++it) {
    const int s = it * 256 + t;
    const int ml = s >> 4, gs = s & 15;
    const int G = gs ^ (ml & 7);  // dest slot gs holds granule G
    const size_t rg = (size_t)ml * (B_ * N_) + c;
    gload_lds16(ximg + (rg >> 7) * 16384 +
                    ((rg & 127) * 16 + (size_t)(G ^ ((int)rg & 7))) * 8,
                &Sx[s * 8]);
  }
  asm volatile("s_waitcnt vmcnt(0)" ::: "memory");
  __syncthreads();

  const int wv = t >> 6, lane = t & 63;
  const int lq = lane >> 4, l16 = lane & 15;

  // --- projection: Q,K,V (32 rows x 32 cols) for this wave's head pair ---
  floatx4 aQ[2][2] = {}, aK[2][2] = {}, aV[2][2] = {};
#pragma unroll
  for (int kk = 0; kk < 4; ++kk) {
    short8 a[2];
#pragma unroll
    for (int i = 0; i < 2; ++i) {
      const int ml = i * 16 + l16;
      a[i] = *(const short8*)&Sx[(ml * 16 + ((kk * 4 + lq) ^ (ml & 7))) * 8];
    }
#pragma unroll
    for (int mat = 0; mat < 3; ++mat) {
      const unsigned short* wb = wimg + mat * 16384;
      short8 bf[2];
#pragma unroll
      for (int j = 0; j < 2; ++j) {
        const int nb = wv * 32 + j * 16 + l16;
        bf[j] =
            *(const short8*)&wb[(nb * 16 + ((kk * 4 + lq) ^ (nb & 7))) * 8];
      }
#pragma unroll
      for (int i = 0; i < 2; ++i)
#pragma unroll
        for (int j = 0; j < 2; ++j) {
          floatx4* acc = mat == 0 ? &aQ[i][j] : (mat == 1 ? &aK[i][j] : &aV[i][j]);
          *acc = __builtin_amdgcn_mfma_f32_16x16x32_bf16(a[i], bf[j], *acc, 0,
                                                         0, 0);
        }
    }
  }
  // --- bias + write Q,K to per-wave scratch (cvt_pk, rows stride 40) ---
  const float bQ0 = bias[wv * 32 + l16], bQ1 = bias[wv * 32 + 16 + l16];
  const float bK0 = bias[128 + wv * 32 + l16],
              bK1 = bias[128 + wv * 32 + 16 + l16];
  const float bV0 = bias[256 + wv * 32 + l16],
              bV1 = bias[256 + wv * 32 + 16 + l16];
  unsigned short* Sq = Sqk[wv][0];
  unsigned short* Sk = Sqk[wv][1];
#pragma unroll
  for (int i = 0; i < 2; ++i)
#pragma unroll
    for (int j = 0; j < 2; ++j) {
      const float qb_ = j ? bQ1 : bQ0, kb_ = j ? bK1 : bK0;
      const unsigned q01 = cvtpk(aQ[i][j][0] + qb_, aQ[i][j][1] + qb_);
      const unsigned q23 = cvtpk(aQ[i][j][2] + qb_, aQ[i][j][3] + qb_);
      const unsigned k01 = cvtpk(aK[i][j][0] + kb_, aK[i][j][1] + kb_);
      const unsigned k23 = cvtpk(aK[i][j][2] + kb_, aK[i][j][3] + kb_);
      unsigned short* q_ = &Sq[(i * 16 + lq * 4) * 40 + j * 16 + l16];
      unsigned short* k_ = &Sk[(i * 16 + lq * 4) * 40 + j * 16 + l16];
      q_[0] = (unsigned short)q01;   q_[40] = (unsigned short)(q01 >> 16);
      q_[80] = (unsigned short)q23;  q_[120] = (unsigned short)(q23 >> 16);
      k_[0] = (unsigned short)k01;   k_[40] = (unsigned short)(k01 >> 16);
      k_[80] = (unsigned short)k23;  k_[120] = (unsigned short)(k23 >> 16);
    }
  // --- output row pointers (head-independent) ---
  unsigned short* ob[8];
  int rsw[8];
#pragma unroll
  for (int lt = 0; lt < 2; ++lt)
#pragma unroll
    for (int r = 0; r < 4; ++r) {
      const int l = lt * 16 + lq * 4 + r;
      const size_t rg = (size_t)l * (B_ * N_) + c;
      ob[lt * 4 + r] = oimg + (rg >> 7) * 16384 + (size_t)(rg & 127) * 128;
      rsw[lt * 4 + r] = (int)(rg & 7);
    }

  const float CSC = 0.25f * 1.4426950408889634f;  // qk scale * log2(e)
#pragma unroll
  for (int hh = 0; hh < 2; ++hh) {
    const int h = wv * 2 + hh;
    // ---- K A-frags / Q B-frags from scratch; k-slots lq>=2 stay zero ----
    short8 ka0 = {}, ka1 = {}, qb0 = {}, qb1 = {};
    if (lq < 2) {
      const int go = (2 * hh + lq) * 8;
      ka0 = *(const short8*)&Sk[l16 * 40 + go];
      ka1 = *(const short8*)&Sk[(16 + l16) * 40 + go];
      qb0 = *(const short8*)&Sq[l16 * 40 + go];
      qb1 = *(const short8*)&Sq[(16 + l16) * 40 + go];
    }
    // ---- S^T = K . Q^T : D row = m_local (lq*4+reg), col = l_local ----
    floatx4 st00 = {}, st01 = {}, st10 = {}, st11 = {};
    st00 = __builtin_amdgcn_mfma_f32_16x16x32_bf16(ka0, qb0, st00, 0, 0, 0);
    st01 = __builtin_amdgcn_mfma_f32_16x16x32_bf16(ka0, qb1, st01, 0, 0, 0);
    st10 = __builtin_amdgcn_mfma_f32_16x16x32_bf16(ka1, qb0, st10, 0, 0, 0);
    st11 = __builtin_amdgcn_mfma_f32_16x16x32_bf16(ka1, qb1, st11, 0, 0, 0);
    // ---- V B-frag directly from proj accumulators (pi-pairing) ----
    const float bV = hh ? bV1 : bV0;
    B8 vu;
    vu.u[0] = cvtpk(aV[0][hh][0] + bV, aV[0][hh][1] + bV);
    vu.u[1] = cvtpk(aV[0][hh][2] + bV, aV[0][hh][3] + bV);
    vu.u[2] = cvtpk(aV[1][hh][0] + bV, aV[1][hh][1] + bV);
    vu.u[3] = cvtpk(aV[1][hh][2] + bV, aV[1][hh][3] + bV);
    const short8 vb = vu.s;
    // ---- softmax per l-column (log2-domain exp); P packed via cvt_pk ----
    short8 pa0, pa1;
    {  // lt = 0: scores from st00 (m 0..15) and st10 (m 16..31)
      floatx4 a = st00 * CSC, cc = st10 * CSC;
      float mx = fmaxf(fmaxf(fmaxf(a[0], a[1]), fmaxf(a[2], a[3])),
                       fmaxf(fmaxf(cc[0], cc[1]), fmaxf(cc[2], cc[3])));
      mx = fmaxf(mx, __shfl_xor(mx, 16));
      mx = fmaxf(mx, __shfl_xor(mx, 32));
      float p0 = vexp2(a[0] - mx), p1 = vexp2(a[1] - mx);
      float p2 = vexp2(a[2] - mx), p3 = vexp2(a[3] - mx);
      float p4 = vexp2(cc[0] - mx), p5 = vexp2(cc[1] - mx);
      float p6 = vexp2(cc[2] - mx), p7 = vexp2(cc[3] - mx);
      float sm = ((p0 + p1) + (p2 + p3)) + ((p4 + p5) + (p6 + p7));
      sm += __shfl_xor(sm, 16);
      sm += __shfl_xor(sm, 32);
      const float inv = vrcp(sm);
      B8 pu;
      pu.u[0] = cvtpk(p0 * inv, p1 * inv);
      pu.u[1] = cvtpk(p2 * inv, p3 * inv);
      pu.u[2] = cvtpk(p4 * inv, p5 * inv);
      pu.u[3] = cvtpk(p6 * inv, p7 * inv);
      pa0 = pu.s;
    }
    {  // lt = 1: scores from st01 and st11
      floatx4 a = st01 * CSC, cc = st11 * CSC;
      float mx = fmaxf(fmaxf(fmaxf(a[0], a[1]), fmaxf(a[2], a[3])),
                       fmaxf(fmaxf(cc[0], cc[1]), fmaxf(cc[2], cc[3])));
      mx = fmaxf(mx, __shfl_xor(mx, 16));
      mx = fmaxf(mx, __shfl_xor(mx, 32));
      float p0 = vexp2(a[0] - mx), p1 = vexp2(a[1] - mx);
      float p2 = vexp2(a[2] - mx), p3 = vexp2(a[3] - mx);
      float p4 = vexp2(cc[0] - mx), p5 = vexp2(cc[1] - mx);
      float p6 = vexp2(cc[2] - mx), p7 = vexp2(cc[3] - mx);
      float sm = ((p0 + p1) + (p2 + p3)) + ((p4 + p5) + (p6 + p7));
      sm += __shfl_xor(sm, 16);
      sm += __shfl_xor(sm, 32);
      const float inv = vrcp(sm);
      B8 pu;
      pu.u[0] = cvtpk(p0 * inv, p1 * inv);
      pu.u[1] = cvtpk(p2 * inv, p3 * inv);
      pu.u[2] = cvtpk(p4 * inv, p5 * inv);
      pu.u[3] = cvtpk(p6 * inv, p7 * inv);
      pa1 = pu.s;
    }
    // ---- O = P.V : D row = l_local (lq*4+reg), col = d_local (l16) ----
    floatx4 o0 = {}, o1 = {};
    o0 = __builtin_amdgcn_mfma_f32_16x16x32_bf16(pa0, vb, o0, 0, 0, 0);
    o1 = __builtin_amdgcn_mfma_f32_16x16x32_bf16(pa1, vb, o1, 0, 0, 0);
    // ---- store this head's d-slice (d = h*16 + l16) into o_t image ----
    const int d = h * 16 + l16;
    const int gd = d >> 3, de = d & 7;
#pragma unroll
    for (int r = 0; r < 4; ++r) {
      const unsigned w = cvtpk(o0[r], o1[r]);
      ob[r][(gd ^ rsw[r]) * 8 + de] = (unsigned short)w;
      ob[4 + r][(gd ^ rsw[4 + r]) * 8 + de] = (unsigned short)(w >> 16);
    }
  }
}

// ---------------------------------------------------------------------------
// sattn_final (R14): spatial attention + output GEMM fused, XCD-pinned,
// Os-only LDS. R7 lesson: 64KB LDS capped occupancy at 2 blocks/CU (34%);
// gather is latency-bound so occupancy is the lever. Bs dropped — W B-frags
// are read directly from the L2-resident pre-swizzled wimg slabs (pattern
// proven in tattn_fused). LDS = 32KB -> 4 blocks/CU (wave-capped, 100%).
// Phase A: gather o_s for 128 consecutive rows into Os (image layout).
// Phase B pass0: acc  = Os(o_s) @ Ws^T (B from global);
//         restage Os <- o_t tile; pass1: acc += o_t @ Wt^T; out=acc+bt+bs.
// ---------------------------------------------------------------------------
__global__ __launch_bounds__(512) void sattn_final(
    const unsigned short* __restrict__ qkv, const int* __restrict__ route,
    const unsigned short* __restrict__ otimg,
    const unsigned short* __restrict__ wtimg,  // t_out image slab
    const unsigned short* __restrict__ wsimg,  // s_out image slab
    const float* __restrict__ bt, const float* __restrict__ bs,
    float* __restrict__ out) {
  __shared__ unsigned short Os[128 * 128];  // o_s image tile; later o_t tile
  const int t = threadIdx.x;
  const int bb = blockIdx.x;
  const int bm = (bb & 7) * 125 + (bb >> 3);  // XCD-pinned tile order
  // --- phase A: o_s for rows bm*128 .. +128 into Os (sattn body) ---
  const int h = t & 7;
#pragma unroll
  for (int it2 = 0; it2 < 2; ++it2) {
    const int rl = (t >> 3) + it2 * 64;       // 0..127
    const int gr = bm * 128 + rl;             // global row
    const int lb = (int)((unsigned)gr / 1000u);
    const int n = gr - lb * 1000;
    float q[16];
    {
      const unsigned short* qp = qkv + (size_t)gr * 384 + h * DH_;
      ushort8v q0 = *(const ushort8v*)qp;
      ushort8v q1 = *(const ushort8v*)(qp + 8);
#pragma unroll
      for (int i = 0; i < 8; ++i) { q[i] = bf2f(q0[i]); q[8 + i] = bf2f(q1[i]); }
    }
    int nb[KN_];
#pragma unroll
    for (int kk = 0; kk < KN_; ++kk) nb[kk] = route[n * KN_ + kk];
    // full preload: all k and v segments issued before any FMA
    ushort8v kr[KN_][2], vr[KN_][2];
#pragma unroll
    for (int kk = 0; kk < KN_; ++kk) {
      const unsigned short* base = qkv + ((size_t)lb * N_ + nb[kk]) * 384;
      const unsigned short* kp = base + 128 + h * DH_;
      const unsigned short* vp = base + 256 + h * DH_;
      kr[kk][0] = *(const ushort8v*)kp;
      kr[kk][1] = *(const ushort8v*)(kp + 8);
      vr[kk][0] = *(const ushort8v*)vp;
      vr[kk][1] = *(const ushort8v*)(vp + 8);
    }
    float sc[KN_];
    float mx = -1e30f;
#pragma unroll
    for (int kk = 0; kk < KN_; ++kk) {
      float d = 0.f;
#pragma unroll
      for (int i = 0; i < 8; ++i) {
        d = fmaf(q[i], bf2f(kr[kk][0][i]), d);
        d = fmaf(q[8 + i], bf2f(kr[kk][1][i]), d);
      }
      d *= 0.25f;
      sc[kk] = d;
      mx = fmaxf(mx, d);
    }
    float ssum = 0.f;
#pragma unroll
    for (int kk = 0; kk < KN_; ++kk) { sc[kk] = __expf(sc[kk] - mx); ssum += sc[kk]; }
    float inv = 1.f / ssum;
    float oa[16];
#pragma unroll
    for (int i = 0; i < 16; ++i) oa[i] = 0.f;
#pragma unroll
    for (int kk = 0; kk < KN_; ++kk) {
      float p = sc[kk] * inv;
#pragma unroll
      for (int i = 0; i < 8; ++i) {
        oa[i] = fmaf(p, bf2f(vr[kk][0][i]), oa[i]);
        oa[8 + i] = fmaf(p, bf2f(vr[kk][1][i]), oa[8 + i]);
      }
    }
    BW8 w0, w1;
    w0.u[0] = cvtpk(oa[0], oa[1]);   w0.u[1] = cvtpk(oa[2], oa[3]);
    w0.u[2] = cvtpk(oa[4], oa[5]);   w0.u[3] = cvtpk(oa[6], oa[7]);
    w1.u[0] = cvtpk(oa[8], oa[9]);   w1.u[1] = cvtpk(oa[10], oa[11]);
    w1.u[2] = cvtpk(oa[12], oa[13]); w1.u[3] = cvtpk(oa[14], oa[15]);
    const int sw = rl & 7;
    *(ushort8v*)(&Os[(size_t)(rl * 16 + ((2 * h) ^ sw)) * 8]) = w0.s;
    *(ushort8v*)(&Os[(size_t)(rl * 16 + ((2 * h + 1) ^ sw)) * 8]) = w1.s;
  }
  __syncthreads();

  // --- phase B: two K=128 GEMM passes; B-frags straight from global ---
  const int wave = t >> 6, lane = t & 63;
  const int wm = (wave >> 2) * 64, wn = (wave & 3) * 32;
  const int lq = lane >> 4, l16 = lane & 15;
  floatx4 acc[4][2] = {};
#pragma unroll
  for (int p = 0; p < 2; ++p) {
    if (p) {
      __syncthreads();  // all waves done reading Os
#pragma unroll
      for (int it = 0; it < 4; ++it) {
        int gi = it * 512 + t;
        gload_lds16(otimg + (size_t)bm * 16384 + (size_t)gi * 8, &Os[gi * 8]);
      }
      asm volatile("s_waitcnt vmcnt(0)" ::: "memory");
      __syncthreads();
    }
    const unsigned short* wsrc = p ? wtimg : wsimg;
#pragma unroll
    for (int kk = 0; kk < 4; ++kk) {
      int g = kk * 4 + lq;
      short8 a[4], b[2];
#pragma unroll
      for (int i = 0; i < 4; ++i) {
        int ma = wm + i * 16 + l16;
        a[i] = *(const short8*)(&Os[(ma * 16 + (g ^ (ma & 7))) * 8]);
      }
#pragma unroll
      for (int j = 0; j < 2; ++j) {
        int nb2 = wn + j * 16 + l16;
        b[j] = *(const short8*)(&wsrc[(nb2 * 16 + (g ^ (nb2 & 7))) * 8]);
      }
#pragma unroll
      for (int i = 0; i < 4; ++i)
#pragma unroll
        for (int j = 0; j < 2; ++j)
          acc[i][j] = __builtin_amdgcn_mfma_f32_16x16x32_bf16(a[i], b[j],
                                                              acc[i][j], 0, 0, 0);
    }
  }
  const size_t rowBase = (size_t)bm * 128 + wm;
#pragma unroll
  for (int j = 0; j < 2; ++j) {
    int col = wn + j * 16 + l16;
    float bb2 = bt[col] + bs[col];
#pragma unroll
    for (int i = 0; i < 4; ++i) {
#pragma unroll
      for (int r = 0; r < 4; ++r) {
        size_t row = rowBase + i * 16 + lq * 4 + r;
        out[row * 128 + col] = acc[i][j][r] + bb2;
      }
    }
  }
}

extern "C" void kernel_launch(void* const* d_in, const int* in_sizes, int n_in,
                              void* d_out, int out_size, void* d_ws,
                              size_t ws_size, hipStream_t stream) {
  const float* x = (const float*)d_in[0];
  const int* route = (const int*)d_in[1];
  const float* t_in_w = (const float*)d_in[2];
  const float* t_in_b = (const float*)d_in[3];
  const float* t_out_w = (const float*)d_in[4];
  const float* t_out_b = (const float*)d_in[5];
  const float* s_in_w = (const float*)d_in[6];
  const float* s_in_b = (const float*)d_in[7];
  const float* s_out_w = (const float*)d_in[8];
  const float* s_out_b = (const float*)d_in[9];
  float* out = (float*)d_out;
  // ws (ushorts): ximg [M*128] | qkv [M*384] | o_t img [M*128] | wimg [8*16384]
  unsigned short* ximg = (unsigned short*)d_ws;
  unsigned short* qkv = ximg + (size_t)M_ * 128;
  unsigned short* o_t = qkv + (size_t)M_ * 384;
  unsigned short* wimg = o_t + (size_t)M_ * 128;

  prep_kernel<<<1008, 256, 0, stream>>>(x, t_in_w, s_in_w, t_out_w, s_out_w,
                                        ximg, wimg);
  tattn_fused<<<B_ * N_, 256, 0, stream>>>(ximg, wimg, t_in_b, o_t);
  proj_mfma<<<(M_ / 128) * 3, 256, 0, stream>>>(ximg, wimg + 3 * 16384,
                                                s_in_b, qkv);
  sattn_final<<<M_ / 128, 512, 0, stream>>>(qkv, route, o_t,
                                            wimg + 6 * 16384, wimg + 7 * 16384,
                                            t_out_b, s_out_b, out);
}

// Round 9
// 248.327 us; speedup vs baseline: 1.1895x; 1.0374x over previous
//
#include <hip/hip_runtime.h>
#include <math.h>

#define L_ 32
#define B_ 4
#define N_ 1000
#define D_ 128
#define H_ 8
#define DH_ 16
#define KN_ 8
#define M_ (L_ * B_ * N_)  // 128000 rows

typedef __attribute__((ext_vector_type(8))) short short8;
typedef __attribute__((ext_vector_type(8))) unsigned short ushort8v;
typedef __attribute__((ext_vector_type(4))) float floatx4;
typedef __attribute__((ext_vector_type(4))) unsigned uintx4;

static __device__ __forceinline__ unsigned short f2bf(float f) {
  union { float f; unsigned u; } v; v.f = f;
  unsigned r = v.u + 0x7fffu + ((v.u >> 16) & 1u);
  return (unsigned short)(r >> 16);
}
static __device__ __forceinline__ float bf2f(unsigned short s) {
  union { unsigned u; float f; } v; v.u = ((unsigned)s) << 16;
  return v.f;
}
// packed 2xf32 -> 2xbf16 (RNE), 1 VALU inst
static __device__ __forceinline__ unsigned cvtpk(float lo, float hi) {
  unsigned r;
  asm("v_cvt_pk_bf16_f32 %0, %1, %2" : "=v"(r) : "v"(lo), "v"(hi));
  return r;
}
static __device__ __forceinline__ float vexp2(float x) {  // 2^x
  float r; asm("v_exp_f32 %0, %1" : "=v"(r) : "v"(x)); return r;
}
static __device__ __forceinline__ float vrcp(float x) {  // ~1ulp 1/x
  float r; asm("v_rcp_f32 %0, %1" : "=v"(r) : "v"(x)); return r;
}
union B8 { uintx4 u; short8 s; };
union BW8 { uintx4 u; ushort8v s; };
// async global->LDS, 16B per lane; LDS dest is wave-uniform base + lane*16.
static __device__ __forceinline__ void gload_lds16(const unsigned short* g,
                                                   unsigned short* l) {
  __builtin_amdgcn_global_load_lds(
      (const __attribute__((address_space(1))) unsigned int*)g,
      (__attribute__((address_space(3))) unsigned int*)l, 16, 0, 0);
}

// ---------------------------------------------------------------------------
// prep_w (R15): weights only — fp32 -> bf16 128x128 tile-images, XOR-swizzled
// granules (granule g of row m at slot m*16 + (g^(m&7))).
// Blocks 0-2: t_in, 3-5: s_in, 6: t_out, 7: s_out. (x images eliminated —
// tattn_sproj converts x in-kernel.)
// ---------------------------------------------------------------------------
__global__ __launch_bounds__(256) void prep_w(
    const float* __restrict__ wt_in, const float* __restrict__ ws_in,
    const float* __restrict__ wt_out, const float* __restrict__ ws_out,
    unsigned short* __restrict__ wimg) {
  const int w = blockIdx.x, t = threadIdx.x;
  const float* src;
  if (w < 3) src = wt_in + (size_t)w * 16384;
  else if (w < 6) src = ws_in + (size_t)(w - 3) * 16384;
  else if (w == 6) src = wt_out;
  else src = ws_out;
  unsigned short* dst = wimg + (size_t)w * 16384;
#pragma unroll
  for (int it = 0; it < 8; ++it) {
    int gi = it * 256 + t;  // 0..2047
    int m = gi >> 4, g = gi & 15;
    const float4* sp = (const float4*)(src + m * 128 + g * 8);
    float4 a = sp[0], b = sp[1];
    ushort8v o;
    o[0] = f2bf(a.x); o[1] = f2bf(a.y); o[2] = f2bf(a.z); o[3] = f2bf(a.w);
    o[4] = f2bf(b.x); o[5] = f2bf(b.y); o[6] = f2bf(b.z); o[7] = f2bf(b.w);
    *(ushort8v*)(dst + (size_t)(m * 16 + (g ^ (m & 7))) * 8) = o;
  }
}

// ---------------------------------------------------------------------------
// tattn_sproj (R15): x-convert + t-path projection + temporal attention +
// s-path projection, all in one kernel per (b,n). 4 waves.
//  stage:  32 x-rows fp32 -> bf16 into Sx (swizzled; same formula as prep).
//  t-path: wave wv owns heads 2wv,2wv+1 — Q,K,V via 48 MFMAs (W from
//          L2-resident t_in image slabs), attention exactly as R11,
//          o_t written to image.
//  s-path: qkv_s = x @ Ws_in^T + bs for ALL 384 cols: wave wv owns
//          col-blocks cb = wv*6..wv*6+5 (16 cols each); 48 MFMAs, B-frags
//          straight from s_in image slabs (3 + cb>>3); paired-cvtpk
//          epilogue stores bf16 to qkv[M][384].
// Eliminates proj_mfma kernel + the ximg intermediate entirely.
// ---------------------------------------------------------------------------
__global__ __launch_bounds__(256) void tattn_sproj(
    const float* __restrict__ x,
    const unsigned short* __restrict__ wimg,  // 8 slabs (t_in 0-2, s_in 3-5)
    const float* __restrict__ bt_in,          // t_in_b[384]
    const float* __restrict__ bs_in,          // s_in_b[384]
    unsigned short* __restrict__ qkv,         // s-path QKV [M][384]
    unsigned short* __restrict__ oimg) {      // o_t image
  __shared__ unsigned short Sx[512 * 8];         // 8KB: x rows 0..31 (bf16)
  __shared__ unsigned short Sqk[4][2][32 * 40];  // 20KB: per-wave Q,K scratch
  const int t = threadIdx.x;
  const int b = blockIdx.x / N_;
  const int n = blockIdx.x % N_;
  const int c = b * N_ + n;
  // --- stage x rows 0..31: thread t -> row ml=t>>3, granules 2*(t&7)+{0,1} ---
  {
    const int ml = t >> 3, s2 = t & 7;
    const float4* sp =
        (const float4*)(x + ((size_t)ml * (B_ * N_) + c) * 128 + s2 * 16);
    float4 a0 = sp[0], a1 = sp[1], a2 = sp[2], a3 = sp[3];
    BW8 o0, o1;
    o0.u[0] = cvtpk(a0.x, a0.y); o0.u[1] = cvtpk(a0.z, a0.w);
    o0.u[2] = cvtpk(a1.x, a1.y); o0.u[3] = cvtpk(a1.z, a1.w);
    o1.u[0] = cvtpk(a2.x, a2.y); o1.u[1] = cvtpk(a2.z, a2.w);
    o1.u[2] = cvtpk(a3.x, a3.y); o1.u[3] = cvtpk(a3.z, a3.w);
    const int g0 = 2 * s2;
    *(ushort8v*)&Sx[(ml * 16 + (g0 ^ (ml & 7))) * 8] = o0.s;
    *(ushort8v*)&Sx[(ml * 16 + ((g0 + 1) ^ (ml & 7))) * 8] = o1.s;
  }
  __syncthreads();

  const int wv = t >> 6, lane = t & 63;
  const int lq = lane >> 4, l16 = lane & 15;

  // --- t-path projection: Q,K,V (32x32) for this wave's head pair ---
  floatx4 aQ[2][2] = {}, aK[2][2] = {}, aV[2][2] = {};
#pragma unroll
  for (int kk = 0; kk < 4; ++kk) {
    short8 a[2];
#pragma unroll
    for (int i = 0; i < 2; ++i) {
      const int ml = i * 16 + l16;
      a[i] = *(const short8*)&Sx[(ml * 16 + ((kk * 4 + lq) ^ (ml & 7))) * 8];
    }
#pragma unroll
    for (int mat = 0; mat < 3; ++mat) {
      const unsigned short* wb = wimg + mat * 16384;
      short8 bf[2];
#pragma unroll
      for (int j = 0; j < 2; ++j) {
        const int nb = wv * 32 + j * 16 + l16;
        bf[j] =
            *(const short8*)&wb[(nb * 16 + ((kk * 4 + lq) ^ (nb & 7))) * 8];
      }
#pragma unroll
      for (int i = 0; i < 2; ++i)
#pragma unroll
        for (int j = 0; j < 2; ++j) {
          floatx4* acc = mat == 0 ? &aQ[i][j] : (mat == 1 ? &aK[i][j] : &aV[i][j]);
          *acc = __builtin_amdgcn_mfma_f32_16x16x32_bf16(a[i], bf[j], *acc, 0,
                                                         0, 0);
        }
    }
  }
  // --- bias + write Q,K to per-wave scratch (cvt_pk, rows stride 40) ---
  const float bQ0 = bt_in[wv * 32 + l16], bQ1 = bt_in[wv * 32 + 16 + l16];
  const float bK0 = bt_in[128 + wv * 32 + l16],
              bK1 = bt_in[128 + wv * 32 + 16 + l16];
  const float bV0 = bt_in[256 + wv * 32 + l16],
              bV1 = bt_in[256 + wv * 32 + 16 + l16];
  unsigned short* Sq = Sqk[wv][0];
  unsigned short* Sk = Sqk[wv][1];
#pragma unroll
  for (int i = 0; i < 2; ++i)
#pragma unroll
    for (int j = 0; j < 2; ++j) {
      const float qb_ = j ? bQ1 : bQ0, kb_ = j ? bK1 : bK0;
      const unsigned q01 = cvtpk(aQ[i][j][0] + qb_, aQ[i][j][1] + qb_);
      const unsigned q23 = cvtpk(aQ[i][j][2] + qb_, aQ[i][j][3] + qb_);
      const unsigned k01 = cvtpk(aK[i][j][0] + kb_, aK[i][j][1] + kb_);
      const unsigned k23 = cvtpk(aK[i][j][2] + kb_, aK[i][j][3] + kb_);
      unsigned short* q_ = &Sq[(i * 16 + lq * 4) * 40 + j * 16 + l16];
      unsigned short* k_ = &Sk[(i * 16 + lq * 4) * 40 + j * 16 + l16];
      q_[0] = (unsigned short)q01;   q_[40] = (unsigned short)(q01 >> 16);
      q_[80] = (unsigned short)q23;  q_[120] = (unsigned short)(q23 >> 16);
      k_[0] = (unsigned short)k01;   k_[40] = (unsigned short)(k01 >> 16);
      k_[80] = (unsigned short)k23;  k_[120] = (unsigned short)(k23 >> 16);
    }
  // --- output row pointers (head-independent) ---
  unsigned short* ob[8];
  int rsw[8];
#pragma unroll
  for (int lt = 0; lt < 2; ++lt)
#pragma unroll
    for (int r = 0; r < 4; ++r) {
      const int l = lt * 16 + lq * 4 + r;
      const size_t rg = (size_t)l * (B_ * N_) + c;
      ob[lt * 4 + r] = oimg + (rg >> 7) * 16384 + (size_t)(rg & 127) * 128;
      rsw[lt * 4 + r] = (int)(rg & 7);
    }

  const float CSC = 0.25f * 1.4426950408889634f;  // qk scale * log2(e)
#pragma unroll
  for (int hh = 0; hh < 2; ++hh) {
    const int h = wv * 2 + hh;
    // ---- K A-frags / Q B-frags from scratch; k-slots lq>=2 stay zero ----
    short8 ka0 = {}, ka1 = {}, qb0 = {}, qb1 = {};
    if (lq < 2) {
      const int go = (2 * hh + lq) * 8;
      ka0 = *(const short8*)&Sk[l16 * 40 + go];
      ka1 = *(const short8*)&Sk[(16 + l16) * 40 + go];
      qb0 = *(const short8*)&Sq[l16 * 40 + go];
      qb1 = *(const short8*)&Sq[(16 + l16) * 40 + go];
    }
    // ---- S^T = K . Q^T : D row = m_local (lq*4+reg), col = l_local ----
    floatx4 st00 = {}, st01 = {}, st10 = {}, st11 = {};
    st00 = __builtin_amdgcn_mfma_f32_16x16x32_bf16(ka0, qb0, st00, 0, 0, 0);
    st01 = __builtin_amdgcn_mfma_f32_16x16x32_bf16(ka0, qb1, st01, 0, 0, 0);
    st10 = __builtin_amdgcn_mfma_f32_16x16x32_bf16(ka1, qb0, st10, 0, 0, 0);
    st11 = __builtin_amdgcn_mfma_f32_16x16x32_bf16(ka1, qb1, st11, 0, 0, 0);
    // ---- V B-frag directly from proj accumulators (pi-pairing) ----
    const float bV = hh ? bV1 : bV0;
    B8 vu;
    vu.u[0] = cvtpk(aV[0][hh][0] + bV, aV[0][hh][1] + bV);
    vu.u[1] = cvtpk(aV[0][hh][2] + bV, aV[0][hh][3] + bV);
    vu.u[2] = cvtpk(aV[1][hh][0] + bV, aV[1][hh][1] + bV);
    vu.u[3] = cvtpk(aV[1][hh][2] + bV, aV[1][hh][3] + bV);
    const short8 vb = vu.s;
    // ---- softmax per l-column (log2-domain exp); P packed via cvt_pk ----
    short8 pa0, pa1;
    {  // lt = 0: scores from st00 (m 0..15) and st10 (m 16..31)
      floatx4 a = st00 * CSC, cc = st10 * CSC;
      float mx = fmaxf(fmaxf(fmaxf(a[0], a[1]), fmaxf(a[2], a[3])),
                       fmaxf(fmaxf(cc[0], cc[1]), fmaxf(cc[2], cc[3])));
      mx = fmaxf(mx, __shfl_xor(mx, 16));
      mx = fmaxf(mx, __shfl_xor(mx, 32));
      float p0 = vexp2(a[0] - mx), p1 = vexp2(a[1] - mx);
      float p2 = vexp2(a[2] - mx), p3 = vexp2(a[3] - mx);
      float p4 = vexp2(cc[0] - mx), p5 = vexp2(cc[1] - mx);
      float p6 = vexp2(cc[2] - mx), p7 = vexp2(cc[3] - mx);
      float sm = ((p0 + p1) + (p2 + p3)) + ((p4 + p5) + (p6 + p7));
      sm += __shfl_xor(sm, 16);
      sm += __shfl_xor(sm, 32);
      const float inv = vrcp(sm);
      B8 pu;
      pu.u[0] = cvtpk(p0 * inv, p1 * inv);
      pu.u[1] = cvtpk(p2 * inv, p3 * inv);
      pu.u[2] = cvtpk(p4 * inv, p5 * inv);
      pu.u[3] = cvtpk(p6 * inv, p7 * inv);
      pa0 = pu.s;
    }
    {  // lt = 1: scores from st01 and st11
      floatx4 a = st01 * CSC, cc = st11 * CSC;
      float mx = fmaxf(fmaxf(fmaxf(a[0], a[1]), fmaxf(a[2], a[3])),
                       fmaxf(fmaxf(cc[0], cc[1]), fmaxf(cc[2], cc[3])));
      mx = fmaxf(mx, __shfl_xor(mx, 16));
      mx = fmaxf(mx, __shfl_xor(mx, 32));
      float p0 = vexp2(a[0] - mx), p1 = vexp2(a[1] - mx);
      float p2 = vexp2(a[2] - mx), p3 = vexp2(a[3] - mx);
      float p4 = vexp2(cc[0] - mx), p5 = vexp2(cc[1] - mx);
      float p6 = vexp2(cc[2] - mx), p7 = vexp2(cc[3] - mx);
      float sm = ((p0 + p1) + (p2 + p3)) + ((p4 + p5) + (p6 + p7));
      sm += __shfl_xor(sm, 16);
      sm += __shfl_xor(sm, 32);
      const float inv = vrcp(sm);
      B8 pu;
      pu.u[0] = cvtpk(p0 * inv, p1 * inv);
      pu.u[1] = cvtpk(p2 * inv, p3 * inv);
      pu.u[2] = cvtpk(p4 * inv, p5 * inv);
      pu.u[3] = cvtpk(p6 * inv, p7 * inv);
      pa1 = pu.s;
    }
    // ---- O = P.V : D row = l_local (lq*4+reg), col = d_local (l16) ----
    floatx4 o0 = {}, o1 = {};
    o0 = __builtin_amdgcn_mfma_f32_16x16x32_bf16(pa0, vb, o0, 0, 0, 0);
    o1 = __builtin_amdgcn_mfma_f32_16x16x32_bf16(pa1, vb, o1, 0, 0, 0);
    // ---- store this head's d-slice (d = h*16 + l16) into o_t image ----
    const int d = h * 16 + l16;
    const int gd = d >> 3, de = d & 7;
#pragma unroll
    for (int r = 0; r < 4; ++r) {
      const unsigned w = cvtpk(o0[r], o1[r]);
      ob[r][(gd ^ rsw[r]) * 8 + de] = (unsigned short)w;
      ob[4 + r][(gd ^ rsw[4 + r]) * 8 + de] = (unsigned short)(w >> 16);
    }
  }

  // --- s-path projection: qkv_s = x @ Ws^T + bs, wave owns cb = wv*6..+5 ---
  floatx4 accs[2][6] = {};
#pragma unroll
  for (int kk = 0; kk < 4; ++kk) {
    const int g = kk * 4 + lq;
    short8 a[2];
#pragma unroll
    for (int i = 0; i < 2; ++i) {
      const int ml = i * 16 + l16;
      a[i] = *(const short8*)&Sx[(ml * 16 + (g ^ (ml & 7))) * 8];
    }
#pragma unroll
    for (int q = 0; q < 6; ++q) {
      const int cb = wv * 6 + q;
      const unsigned short* wb = wimg + (size_t)(3 + (cb >> 3)) * 16384;
      const int nbt = (cb & 7) * 16 + l16;
      const short8 bf =
          *(const short8*)&wb[(nbt * 16 + (g ^ (nbt & 7))) * 8];
      accs[0][q] =
          __builtin_amdgcn_mfma_f32_16x16x32_bf16(a[0], bf, accs[0][q], 0, 0, 0);
      accs[1][q] =
          __builtin_amdgcn_mfma_f32_16x16x32_bf16(a[1], bf, accs[1][q], 0, 0, 0);
    }
  }
  // epilogue: 48 bf16 stores/thread, paired cvt_pk over row pairs
#pragma unroll
  for (int q = 0; q < 6; ++q) {
    const int col = (wv * 6 + q) * 16 + l16;
    const float bb = bs_in[col];
#pragma unroll
    for (int i = 0; i < 2; ++i) {
      const unsigned u01 = cvtpk(accs[i][q][0] + bb, accs[i][q][1] + bb);
      const unsigned u23 = cvtpk(accs[i][q][2] + bb, accs[i][q][3] + bb);
      const size_t r0 = ((size_t)(i * 16 + lq * 4) * (B_ * N_) + c) * 384 + col;
      qkv[r0] = (unsigned short)u01;
      qkv[r0 + (size_t)(B_ * N_) * 384] = (unsigned short)(u01 >> 16);
      qkv[r0 + (size_t)2 * (B_ * N_) * 384] = (unsigned short)u23;
      qkv[r0 + (size_t)3 * (B_ * N_) * 384] = (unsigned short)(u23 >> 16);
    }
  }
}

// ---------------------------------------------------------------------------
// sattn_final (R14, unchanged): spatial attention + output GEMM fused,
// XCD-pinned (bm = (bb&7)*125 + bb>>3), Os-only 32KB LDS; W B-frags from
// L2-resident weight images.
// ---------------------------------------------------------------------------
__global__ __launch_bounds__(512) void sattn_final(
    const unsigned short* __restrict__ qkv, const int* __restrict__ route,
    const unsigned short* __restrict__ otimg,
    const unsigned short* __restrict__ wtimg,  // t_out image slab
    const unsigned short* __restrict__ wsimg,  // s_out image slab
    const float* __restrict__ bt, const float* __restrict__ bs,
    float* __restrict__ out) {
  __shared__ unsigned short Os[128 * 128];  // o_s image tile; later o_t tile
  const int t = threadIdx.x;
  const int bb = blockIdx.x;
  const int bm = (bb & 7) * 125 + (bb >> 3);  // XCD-pinned tile order
  // --- phase A: o_s for rows bm*128 .. +128 into Os (sattn body) ---
  const int h = t & 7;
#pragma unroll
  for (int it2 = 0; it2 < 2; ++it2) {
    const int rl = (t >> 3) + it2 * 64;       // 0..127
    const int gr = bm * 128 + rl;             // global row
    const int lb = (int)((unsigned)gr / 1000u);
    const int n = gr - lb * 1000;
    float q[16];
    {
      const unsigned short* qp = qkv + (size_t)gr * 384 + h * DH_;
      ushort8v q0 = *(const ushort8v*)qp;
      ushort8v q1 = *(const ushort8v*)(qp + 8);
#pragma unroll
      for (int i = 0; i < 8; ++i) { q[i] = bf2f(q0[i]); q[8 + i] = bf2f(q1[i]); }
    }
    int nb[KN_];
#pragma unroll
    for (int kk = 0; kk < KN_; ++kk) nb[kk] = route[n * KN_ + kk];
    // full preload: all k and v segments issued before any FMA
    ushort8v kr[KN_][2], vr[KN_][2];
#pragma unroll
    for (int kk = 0; kk < KN_; ++kk) {
      const unsigned short* base = qkv + ((size_t)lb * N_ + nb[kk]) * 384;
      const unsigned short* kp = base + 128 + h * DH_;
      const unsigned short* vp = base + 256 + h * DH_;
      kr[kk][0] = *(const ushort8v*)kp;
      kr[kk][1] = *(const ushort8v*)(kp + 8);
      vr[kk][0] = *(const ushort8v*)vp;
      vr[kk][1] = *(const ushort8v*)(vp + 8);
    }
    float sc[KN_];
    float mx = -1e30f;
#pragma unroll
    for (int kk = 0; kk < KN_; ++kk) {
      float d = 0.f;
#pragma unroll
      for (int i = 0; i < 8; ++i) {
        d = fmaf(q[i], bf2f(kr[kk][0][i]), d);
        d = fmaf(q[8 + i], bf2f(kr[kk][1][i]), d);
      }
      d *= 0.25f;
      sc[kk] = d;
      mx = fmaxf(mx, d);
    }
    float ssum = 0.f;
#pragma unroll
    for (int kk = 0; kk < KN_; ++kk) { sc[kk] = __expf(sc[kk] - mx); ssum += sc[kk]; }
    float inv = 1.f / ssum;
    float oa[16];
#pragma unroll
    for (int i = 0; i < 16; ++i) oa[i] = 0.f;
#pragma unroll
    for (int kk = 0; kk < KN_; ++kk) {
      float p = sc[kk] * inv;
#pragma unroll
      for (int i = 0; i < 8; ++i) {
        oa[i] = fmaf(p, bf2f(vr[kk][0][i]), oa[i]);
        oa[8 + i] = fmaf(p, bf2f(vr[kk][1][i]), oa[8 + i]);
      }
    }
    BW8 w0, w1;
    w0.u[0] = cvtpk(oa[0], oa[1]);   w0.u[1] = cvtpk(oa[2], oa[3]);
    w0.u[2] = cvtpk(oa[4], oa[5]);   w0.u[3] = cvtpk(oa[6], oa[7]);
    w1.u[0] = cvtpk(oa[8], oa[9]);   w1.u[1] = cvtpk(oa[10], oa[11]);
    w1.u[2] = cvtpk(oa[12], oa[13]); w1.u[3] = cvtpk(oa[14], oa[15]);
    const int sw = rl & 7;
    *(ushort8v*)(&Os[(size_t)(rl * 16 + ((2 * h) ^ sw)) * 8]) = w0.s;
    *(ushort8v*)(&Os[(size_t)(rl * 16 + ((2 * h + 1) ^ sw)) * 8]) = w1.s;
  }
  __syncthreads();

  // --- phase B: two K=128 GEMM passes; B-frags straight from global ---
  const int wave = t >> 6, lane = t & 63;
  const int wm = (wave >> 2) * 64, wn = (wave & 3) * 32;
  const int lq = lane >> 4, l16 = lane & 15;
  floatx4 acc[4][2] = {};
#pragma unroll
  for (int p = 0; p < 2; ++p) {
    if (p) {
      __syncthreads();  // all waves done reading Os
#pragma unroll
      for (int it = 0; it < 4; ++it) {
        int gi = it * 512 + t;
        gload_lds16(otimg + (size_t)bm * 16384 + (size_t)gi * 8, &Os[gi * 8]);
      }
      asm volatile("s_waitcnt vmcnt(0)" ::: "memory");
      __syncthreads();
    }
    const unsigned short* wsrc = p ? wtimg : wsimg;
#pragma unroll
    for (int kk = 0; kk < 4; ++kk) {
      int g = kk * 4 + lq;
      short8 a[4], b[2];
#pragma unroll
      for (int i = 0; i < 4; ++i) {
        int ma = wm + i * 16 + l16;
        a[i] = *(const short8*)(&Os[(ma * 16 + (g ^ (ma & 7))) * 8]);
      }
#pragma unroll
      for (int j = 0; j < 2; ++j) {
        int nb2 = wn + j * 16 + l16;
        b[j] = *(const short8*)(&wsrc[(nb2 * 16 + (g ^ (nb2 & 7))) * 8]);
      }
#pragma unroll
      for (int i = 0; i < 4; ++i)
#pragma unroll
        for (int j = 0; j < 2; ++j)
          acc[i][j] = __builtin_amdgcn_mfma_f32_16x16x32_bf16(a[i], b[j],
                                                              acc[i][j], 0, 0, 0);
    }
  }
  const size_t rowBase = (size_t)bm * 128 + wm;
#pragma unroll
  for (int j = 0; j < 2; ++j) {
    int col = wn + j * 16 + l16;
    float bb2 = bt[col] + bs[col];
#pragma unroll
    for (int i = 0; i < 4; ++i) {
#pragma unroll
      for (int r = 0; r < 4; ++r) {
        size_t row = rowBase + i * 16 + lq * 4 + r;
        out[row * 128 + col] = acc[i][j][r] + bb2;
      }
    }
  }
}

extern "C" void kernel_launch(void* const* d_in, const int* in_sizes, int n_in,
                              void* d_out, int out_size, void* d_ws,
                              size_t ws_size, hipStream_t stream) {
  const float* x = (const float*)d_in[0];
  const int* route = (const int*)d_in[1];
  const float* t_in_w = (const float*)d_in[2];
  const float* t_in_b = (const float*)d_in[3];
  const float* t_out_w = (const float*)d_in[4];
  const float* t_out_b = (const float*)d_in[5];
  const float* s_in_w = (const float*)d_in[6];
  const float* s_in_b = (const float*)d_in[7];
  const float* s_out_w = (const float*)d_in[8];
  const float* s_out_b = (const float*)d_in[9];
  float* out = (float*)d_out;
  // ws (ushorts): qkv [M*384] | o_t img [M*128] | wimg [8*16384]  (131 MB)
  unsigned short* qkv = (unsigned short*)d_ws;
  unsigned short* o_t = qkv + (size_t)M_ * 384;
  unsigned short* wimg = o_t + (size_t)M_ * 128;

  prep_w<<<8, 256, 0, stream>>>(t_in_w, s_in_w, t_out_w, s_out_w, wimg);
  tattn_sproj<<<B_ * N_, 256, 0, stream>>>(x, wimg, t_in_b, s_in_b, qkv, o_t);
  sattn_final<<<M_ / 128, 512, 0, stream>>>(qkv, route, o_t,
                                            wimg + 6 * 16384, wimg + 7 * 16384,
                                            t_out_b, s_out_b, out);
}